// Round 9
// baseline (1836.486 us; speedup 1.0000x reference)
//
#include <hip/hip_runtime.h>

#define DIM 128
#define BN_EPS 1e-5f
typedef unsigned int u32;
typedef __attribute__((ext_vector_type(8))) short short8;
typedef __attribute__((ext_vector_type(4))) float f32x4;

__device__ __forceinline__ u32 bf16rne(float x) {
  u32 u = __float_as_uint(x);
  return (u + 0x7FFFu + ((u >> 16) & 1u)) >> 16;
}
__device__ __forceinline__ float bflo(u32 u) { return __uint_as_float(u << 16); }
__device__ __forceinline__ float bfhi(u32 u) { return __uint_as_float(u & 0xFFFF0000u); }

// ---------------- CSR build ----------------

__global__ __launch_bounds__(256) void k_count(const int* __restrict__ dst,
                                               int* __restrict__ ideg, int ne) {
  int stride = gridDim.x * blockDim.x;
  for (int e = blockIdx.x * blockDim.x + threadIdx.x; e < ne; e += stride)
    atomicAdd(&ideg[dst[e]], 1);
}

// scan + dinv fused
__global__ __launch_bounds__(1024) void k_scan(const int* __restrict__ ideg,
                                               int* __restrict__ off,
                                               int* __restrict__ cur,
                                               float* __restrict__ dinv, int n) {
  __shared__ int sums[1024];
  int t = threadIdx.x;
  int chunk = (n + 1023) >> 10;
  int s0 = t * chunk;
  int s1 = s0 + chunk;
  if (s0 > n) s0 = n;
  if (s1 > n) s1 = n;
  int tot = 0;
  for (int i = s0; i < s1; ++i) tot += ideg[i];
  sums[t] = tot;
  __syncthreads();
  for (int d = 1; d < 1024; d <<= 1) {
    int v = (t >= d) ? sums[t - d] : 0;
    __syncthreads();
    sums[t] += v;
    __syncthreads();
  }
  int run = (t == 0) ? 0 : sums[t - 1];
  for (int i = s0; i < s1; ++i) {
    off[i] = run;
    cur[i] = run;
    run += ideg[i];
    dinv[i] = rsqrtf((float)ideg[i] + 1.0f);  // +1 = self loop
  }
  if (t == 1023) off[n] = run;
}

__global__ __launch_bounds__(256) void k_fill(const int* __restrict__ src,
                                              const int* __restrict__ dst,
                                              int* __restrict__ cur,
                                              int* __restrict__ csr_src, int ne) {
  int stride = gridDim.x * blockDim.x;
  for (int e = blockIdx.x * blockDim.x + threadIdx.x; e < ne; e += stride) {
    int d = dst[e];
    int s = src[e];
    int p = atomicAdd(&cur[d], 1);
    csr_src[p] = s;
  }
}

// ---------------- W prep: Wt[c][k] bf16-packed, per layer ----------------

__global__ __launch_bounds__(256) void k_wprep(const float* __restrict__ W0,
                                               const float* __restrict__ W1,
                                               const float* __restrict__ W2,
                                               u32* __restrict__ Wt) {
  const float* W = blockIdx.x == 0 ? W0 : (blockIdx.x == 1 ? W1 : W2);
  u32* o = Wt + (size_t)blockIdx.x * DIM * 64;
  int tid = threadIdx.x;
#pragma unroll
  for (int i = 0; i < 32; ++i) {
    int u = tid + i * 256;       // 8192 outputs: Wt[c][kk] = W[2kk][c] | W[2kk+1][c]
    int c = u >> 6;
    int kk = u & 63;
    float lo = W[(size_t)(2 * kk) * DIM + c];
    float hi = W[(size_t)(2 * kk + 1) * DIM + c];
    o[u] = bf16rne(lo) | (bf16rne(hi) << 16);
  }
}

// ---------------- MFMA GEMM: C_bf16[n,128] = dinv[row]*(f(A)[n,128] @ W) ----
// f(A) = relu(A*sc+sh) when sc != null. Wt is bf16-packed W^T (u32[128][64]).
// Block: 128 rows, 4 waves; wave w -> rows [w*32, w*32+32), all 128 cols.

__global__ __launch_bounds__(256) void k_gemm(const float* __restrict__ A,
                                              const u32* __restrict__ Wt,
                                              const float* __restrict__ dinv,
                                              const float* __restrict__ sc,
                                              const float* __restrict__ sh,
                                              u32* __restrict__ C, int n) {
  __shared__ u32 sA[8192];   // 128 rows x 16 slots x 16B, slot-swizzled
  __shared__ u32 sB[8192];   // Wt same layout
  __shared__ float sdv[DIM];
  int tid = threadIdx.x;
  int row0 = blockIdx.x * DIM;

  // stage Wt (already bf16): 2048 uint4 units
  {
    const uint4* w4 = (const uint4*)Wt;
#pragma unroll
    for (int i = 0; i < 8; ++i) {
      int u = tid + i * 256;
      int r = u >> 4, s = u & 15;
      uint4 v = w4[u];
      ((uint4*)sB)[r * 16 + (s ^ (r & 7))] = v;
    }
  }
  // stage A: f32 -> (bn,relu) -> bf16
#pragma unroll
  for (int i = 0; i < 8; ++i) {
    int u = tid + i * 256;
    int r = u >> 4, s = u & 15;
    int gr = row0 + r;
    uint4 pv = make_uint4(0u, 0u, 0u, 0u);
    if (gr < n) {
      float4 v0 = ((const float4*)A)[(size_t)gr * 32 + s * 2];
      float4 v1 = ((const float4*)A)[(size_t)gr * 32 + s * 2 + 1];
      if (sc) {
        float4 s0 = ((const float4*)sc)[s * 2];
        float4 s1 = ((const float4*)sc)[s * 2 + 1];
        float4 h0 = ((const float4*)sh)[s * 2];
        float4 h1 = ((const float4*)sh)[s * 2 + 1];
        v0.x = fmaxf(fmaf(v0.x, s0.x, h0.x), 0.f);
        v0.y = fmaxf(fmaf(v0.y, s0.y, h0.y), 0.f);
        v0.z = fmaxf(fmaf(v0.z, s0.z, h0.z), 0.f);
        v0.w = fmaxf(fmaf(v0.w, s0.w, h0.w), 0.f);
        v1.x = fmaxf(fmaf(v1.x, s1.x, h1.x), 0.f);
        v1.y = fmaxf(fmaf(v1.y, s1.y, h1.y), 0.f);
        v1.z = fmaxf(fmaf(v1.z, s1.z, h1.z), 0.f);
        v1.w = fmaxf(fmaf(v1.w, s1.w, h1.w), 0.f);
      }
      pv.x = bf16rne(v0.x) | (bf16rne(v0.y) << 16);
      pv.y = bf16rne(v0.z) | (bf16rne(v0.w) << 16);
      pv.z = bf16rne(v1.x) | (bf16rne(v1.y) << 16);
      pv.w = bf16rne(v1.z) | (bf16rne(v1.w) << 16);
    }
    ((uint4*)sA)[r * 16 + (s ^ (r & 7))] = pv;
  }
  if (tid < DIM) sdv[tid] = (row0 + tid < n) ? dinv[row0 + tid] : 0.f;
  __syncthreads();

  int lane = tid & 63;
  int w = tid >> 6;
  int lr = lane & 15;
  int g = lane >> 4;
  f32x4 acc[2][8];
#pragma unroll
  for (int m = 0; m < 2; ++m)
#pragma unroll
    for (int nt = 0; nt < 8; ++nt) acc[m][nt] = (f32x4){0.f, 0.f, 0.f, 0.f};

#pragma unroll
  for (int kc = 0; kc < 4; ++kc) {
    short8 a[2], b[8];
#pragma unroll
    for (int m = 0; m < 2; ++m) {
      int r = w * 32 + m * 16 + lr;
      int sp = (kc * 4 + g) ^ (r & 7);
      a[m] = *(const short8*)&sA[(r * 16 + sp) * 4];
    }
#pragma unroll
    for (int nt = 0; nt < 8; ++nt) {
      int r = nt * 16 + lr;
      int sp = (kc * 4 + g) ^ (r & 7);
      b[nt] = *(const short8*)&sB[(r * 16 + sp) * 4];
    }
#pragma unroll
    for (int m = 0; m < 2; ++m)
#pragma unroll
      for (int nt = 0; nt < 8; ++nt)
        acc[m][nt] = __builtin_amdgcn_mfma_f32_16x16x32_bf16(a[m], b[nt], acc[m][nt], 0, 0, 0);
  }
  __syncthreads();

  // epilogue: scale by dinv, pack bf16 into sA (col-block swizzled), copy out
  {
    unsigned short* so = (unsigned short*)sA;
#pragma unroll
    for (int m = 0; m < 2; ++m) {
#pragma unroll
      for (int nt = 0; nt < 8; ++nt) {
#pragma unroll
        for (int r4 = 0; r4 < 4; ++r4) {
          int rl = w * 32 + m * 16 + g * 4 + r4;
          int col = ((nt ^ ((rl >> 2) & 7)) << 4) + lr;  // 16-col-block swizzle
          so[rl * DIM + col] = (unsigned short)bf16rne(acc[m][nt][r4] * sdv[rl]);
        }
      }
    }
  }
  __syncthreads();
#pragma unroll
  for (int i = 0; i < 8; ++i) {
    int u = tid + i * 256;
    int r = u >> 4, s = u & 15;
    if (row0 + r < n) {
      int sswz = (s & 1) | (((s >> 1) ^ ((r >> 2) & 7)) << 1);
      ((uint4*)C)[(size_t)(row0 + r) * 16 + s] = ((uint4*)sA)[r * 16 + sswz];
    }
  }
}

// ---------------- Aggregation + bias + residual(BN-fused) + BN partial stats ----

__global__ __launch_bounds__(256) void k_agg(const u32* __restrict__ xw,
                                             const int* __restrict__ off,
                                             const int* __restrict__ csr_src,
                                             const float* __restrict__ dinv,
                                             const float* __restrict__ bias,
                                             const float* __restrict__ prev,
                                             const float* __restrict__ psc,
                                             const float* __restrict__ psh,
                                             float* __restrict__ out,
                                             float* __restrict__ ssum,
                                             float* __restrict__ ssq, int n) {
  int tid = threadIdx.x;
  int lane = tid & 31;
  int grp = tid >> 5;
  const uint2* xw2 = (const uint2*)xw;
  float4 bc = ((const float4*)bias)[lane];
  float4 ps, ph;
  if (psc) {
    ps = ((const float4*)psc)[lane];
    ph = ((const float4*)psh)[lane];
  }
  float4 lsum = make_float4(0.f, 0.f, 0.f, 0.f);
  float4 lsq = make_float4(0.f, 0.f, 0.f, 0.f);

  for (int node = blockIdx.x * 8 + grp; node < n; node += gridDim.x * 8) {
    int e0 = off[node];
    int e1 = off[node + 1];
    float a0, a1, a2, a3;
    {
      uint2 s = xw2[(size_t)node * 32 + lane];
      a0 = bflo(s.x);
      a1 = bfhi(s.x);
      a2 = bflo(s.y);
      a3 = bfhi(s.y);
    }
    int e = e0;
    for (; e + 8 <= e1; e += 8) {
      int i0 = csr_src[e];
      int i1 = csr_src[e + 1];
      int i2 = csr_src[e + 2];
      int i3 = csr_src[e + 3];
      int i4 = csr_src[e + 4];
      int i5 = csr_src[e + 5];
      int i6 = csr_src[e + 6];
      int i7 = csr_src[e + 7];
      uint2 v0 = xw2[(size_t)i0 * 32 + lane];
      uint2 v1 = xw2[(size_t)i1 * 32 + lane];
      uint2 v2 = xw2[(size_t)i2 * 32 + lane];
      uint2 v3 = xw2[(size_t)i3 * 32 + lane];
      uint2 v4 = xw2[(size_t)i4 * 32 + lane];
      uint2 v5 = xw2[(size_t)i5 * 32 + lane];
      uint2 v6 = xw2[(size_t)i6 * 32 + lane];
      uint2 v7 = xw2[(size_t)i7 * 32 + lane];
      a0 += ((bflo(v0.x) + bflo(v1.x)) + (bflo(v2.x) + bflo(v3.x))) +
            ((bflo(v4.x) + bflo(v5.x)) + (bflo(v6.x) + bflo(v7.x)));
      a1 += ((bfhi(v0.x) + bfhi(v1.x)) + (bfhi(v2.x) + bfhi(v3.x))) +
            ((bfhi(v4.x) + bfhi(v5.x)) + (bfhi(v6.x) + bfhi(v7.x)));
      a2 += ((bflo(v0.y) + bflo(v1.y)) + (bflo(v2.y) + bflo(v3.y))) +
            ((bflo(v4.y) + bflo(v5.y)) + (bflo(v6.y) + bflo(v7.y)));
      a3 += ((bfhi(v0.y) + bfhi(v1.y)) + (bfhi(v2.y) + bfhi(v3.y))) +
            ((bfhi(v4.y) + bfhi(v5.y)) + (bfhi(v6.y) + bfhi(v7.y)));
    }
    for (; e + 4 <= e1; e += 4) {
      int i0 = csr_src[e];
      int i1 = csr_src[e + 1];
      int i2 = csr_src[e + 2];
      int i3 = csr_src[e + 3];
      uint2 v0 = xw2[(size_t)i0 * 32 + lane];
      uint2 v1 = xw2[(size_t)i1 * 32 + lane];
      uint2 v2 = xw2[(size_t)i2 * 32 + lane];
      uint2 v3 = xw2[(size_t)i3 * 32 + lane];
      a0 += (bflo(v0.x) + bflo(v1.x)) + (bflo(v2.x) + bflo(v3.x));
      a1 += (bfhi(v0.x) + bfhi(v1.x)) + (bfhi(v2.x) + bfhi(v3.x));
      a2 += (bflo(v0.y) + bflo(v1.y)) + (bflo(v2.y) + bflo(v3.y));
      a3 += (bfhi(v0.y) + bfhi(v1.y)) + (bfhi(v2.y) + bfhi(v3.y));
    }
    for (; e < e1; ++e) {
      uint2 v = xw2[(size_t)csr_src[e] * 32 + lane];
      a0 += bflo(v.x);
      a1 += bfhi(v.x);
      a2 += bflo(v.y);
      a3 += bfhi(v.y);
    }
    float di = dinv[node];
    float4 v;
    v.x = fmaf(di, a0, bc.x);
    v.y = fmaf(di, a1, bc.y);
    v.z = fmaf(di, a2, bc.z);
    v.w = fmaf(di, a3, bc.w);
    if (prev) {
      float4 pv = ((const float4*)prev)[(size_t)node * 32 + lane];
      if (psc) {
        pv.x = fmaxf(fmaf(pv.x, ps.x, ph.x), 0.f);
        pv.y = fmaxf(fmaf(pv.y, ps.y, ph.y), 0.f);
        pv.z = fmaxf(fmaf(pv.z, ps.z, ph.z), 0.f);
        pv.w = fmaxf(fmaf(pv.w, ps.w, ph.w), 0.f);
      }
      v.x += pv.x;
      v.y += pv.y;
      v.z += pv.z;
      v.w += pv.w;
    }
    ((float4*)out)[(size_t)node * 32 + lane] = v;
    lsum.x += v.x;
    lsum.y += v.y;
    lsum.z += v.z;
    lsum.w += v.w;
    lsq.x = fmaf(v.x, v.x, lsq.x);
    lsq.y = fmaf(v.y, v.y, lsq.y);
    lsq.z = fmaf(v.z, v.z, lsq.z);
    lsq.w = fmaf(v.w, v.w, lsq.w);
  }

  __shared__ float4 red[256];
  red[tid] = lsum;
  __syncthreads();
  if (grp == 0) {
    float4 s = red[lane];
#pragma unroll
    for (int g = 1; g < 8; ++g) {
      float4 t = red[g * 32 + lane];
      s.x += t.x;
      s.y += t.y;
      s.z += t.z;
      s.w += t.w;
    }
    atomicAdd(&ssum[lane * 4 + 0], s.x);
    atomicAdd(&ssum[lane * 4 + 1], s.y);
    atomicAdd(&ssum[lane * 4 + 2], s.z);
    atomicAdd(&ssum[lane * 4 + 3], s.w);
  }
  __syncthreads();
  red[tid] = lsq;
  __syncthreads();
  if (grp == 0) {
    float4 s = red[lane];
#pragma unroll
    for (int g = 1; g < 8; ++g) {
      float4 t = red[g * 32 + lane];
      s.x += t.x;
      s.y += t.y;
      s.z += t.z;
      s.w += t.w;
    }
    atomicAdd(&ssq[lane * 4 + 0], s.x);
    atomicAdd(&ssq[lane * 4 + 1], s.y);
    atomicAdd(&ssq[lane * 4 + 2], s.z);
    atomicAdd(&ssq[lane * 4 + 3], s.w);
  }
}

// ---------------- BN finalize + final normalize/relu ----------------

__global__ void k_bn(const float* __restrict__ ssum, const float* __restrict__ ssq,
                     const float* __restrict__ gamma, const float* __restrict__ beta,
                     float* __restrict__ scale, float* __restrict__ shift, float invn) {
  int c = threadIdx.x;
  float mu = ssum[c] * invn;
  float var = ssq[c] * invn - mu * mu;
  float rstd = rsqrtf(var + BN_EPS);
  float s = rstd * gamma[c];
  scale[c] = s;
  shift[c] = beta[c] - mu * s;
}

__global__ __launch_bounds__(256) void k_norm(const float* __restrict__ in,
                                              float* __restrict__ out,
                                              const float* __restrict__ scale,
                                              const float* __restrict__ shift, int n4) {
  int stride = gridDim.x * blockDim.x;
  for (int i = blockIdx.x * blockDim.x + threadIdx.x; i < n4; i += stride) {
    int cg = i & 31;
    float4 sc = ((const float4*)scale)[cg];
    float4 sh = ((const float4*)shift)[cg];
    float4 v = ((const float4*)in)[i];
    v.x = fmaxf(fmaf(v.x, sc.x, sh.x), 0.f);
    v.y = fmaxf(fmaf(v.y, sc.y, sh.y), 0.f);
    v.z = fmaxf(fmaf(v.z, sc.z, sh.z), 0.f);
    v.w = fmaxf(fmaf(v.w, sc.w, sh.w), 0.f);
    ((float4*)out)[i] = v;
  }
}

// ---------------- launch ----------------

extern "C" void kernel_launch(void* const* d_in, const int* in_sizes, int n_in,
                              void* d_out, int out_size, void* d_ws, size_t ws_size,
                              hipStream_t stream) {
  const float* x = (const float*)d_in[0];
  const int* ei = (const int*)d_in[1];
  int n = in_sizes[0] / DIM;   // 100000
  int ne = in_sizes[1] / 2;    // 1600000
  const int* src = ei;
  const int* dst = ei + ne;

  const float *W[3], *B[3], *G[3], *Bt[3];
  if (n_in >= 14) {
    for (int l = 0; l < 3; ++l) {
      W[l] = (const float*)d_in[2 + l];
      B[l] = (const float*)d_in[5 + l];
      G[l] = (const float*)d_in[8 + l];
      Bt[l] = (const float*)d_in[11 + l];
    }
  } else {
    for (int l = 0; l < 3; ++l) {
      W[l] = (const float*)d_in[2] + (size_t)l * DIM * DIM;
      B[l] = (const float*)d_in[3] + (size_t)l * DIM;
      G[l] = (const float*)d_in[4] + (size_t)l * DIM;
      Bt[l] = (const float*)d_in[5] + (size_t)l * DIM;
    }
  }

  float* out = (float*)d_out;

  char* p = (char*)d_ws;
  auto carve = [&](size_t bytes) {
    void* q = (void*)p;
    p += (bytes + 255) & ~(size_t)255;
    return q;
  };
  int* ideg = (int*)carve((size_t)n * 4);
  int* coff = (int*)carve((size_t)(n + 1) * 4);
  int* cur = (int*)carve((size_t)n * 4);
  float* dinv = (float*)carve((size_t)n * 4);
  int* csr_src = (int*)carve((size_t)ne * 4);
  u32* xw = (u32*)carve((size_t)n * DIM * 2);   // bf16 packed
  float* buf1 = (float*)carve((size_t)n * DIM * 4);
  u32* wt = (u32*)carve(3 * DIM * 64 * 4);      // bf16-packed W^T x3
  float* stats = (float*)carve(3 * 256 * 4);
  float* scsh = (float*)carve(3 * 256 * 4);

  hipMemsetAsync(ideg, 0, (size_t)n * 4, stream);
  hipMemsetAsync(stats, 0, 3 * 256 * 4, stream);

  k_wprep<<<3, 256, 0, stream>>>(W[0], W[1], W[2], wt);
  k_count<<<1024, 256, 0, stream>>>(dst, ideg, ne);
  k_scan<<<1, 1024, 0, stream>>>(ideg, coff, cur, dinv, n);
  k_fill<<<1024, 256, 0, stream>>>(src, dst, cur, csr_src, ne);

  float invn = 1.0f / (float)n;
  int nblk = (n + DIM - 1) / DIM;
  const int AGG_GRID = 4096;

  // layer 0
  float* ss0 = stats;         float* sc0 = scsh;
  k_gemm<<<nblk, 256, 0, stream>>>(x, wt, dinv, nullptr, nullptr, xw, n);
  k_agg<<<AGG_GRID, 256, 0, stream>>>(xw, coff, csr_src, dinv, B[0], nullptr, nullptr, nullptr,
                                      buf1, ss0, ss0 + 128, n);
  k_bn<<<1, 128, 0, stream>>>(ss0, ss0 + 128, G[0], Bt[0], sc0, sc0 + 128, invn);

  // layer 1
  float* ss1 = stats + 256;   float* sc1 = scsh + 256;
  k_gemm<<<nblk, 256, 0, stream>>>(buf1, wt + (size_t)DIM * 64, dinv, sc0, sc0 + 128, xw, n);
  k_agg<<<AGG_GRID, 256, 0, stream>>>(xw, coff, csr_src, dinv, B[1], buf1, sc0, sc0 + 128,
                                      out, ss1, ss1 + 128, n);
  k_bn<<<1, 128, 0, stream>>>(ss1, ss1 + 128, G[1], Bt[1], sc1, sc1 + 128, invn);

  // layer 2
  float* ss2 = stats + 512;   float* sc2 = scsh + 512;
  k_gemm<<<nblk, 256, 0, stream>>>(out, wt + (size_t)2 * DIM * 64, dinv, sc1, sc1 + 128, xw, n);
  k_agg<<<AGG_GRID, 256, 0, stream>>>(xw, coff, csr_src, dinv, B[2], out, sc1, sc1 + 128,
                                      buf1, ss2, ss2 + 128, n);
  k_bn<<<1, 128, 0, stream>>>(ss2, ss2 + 128, G[2], Bt[2], sc2, sc2 + 128, invn);

  // final normalize into d_out
  k_norm<<<2048, 256, 0, stream>>>(buf1, out, sc2, sc2 + 128, n * DIM / 4);
}

// Round 10
// 1036.342 us; speedup vs baseline: 1.7721x; 1.7721x over previous
//
#include <hip/hip_runtime.h>

#define DIM 128
#define BN_EPS 1e-5f
typedef unsigned int u32;
typedef __attribute__((ext_vector_type(8))) short short8;
typedef __attribute__((ext_vector_type(4))) float f32x4;

__device__ __forceinline__ u32 bf16rne(float x) {
  u32 u = __float_as_uint(x);
  return (u + 0x7FFFu + ((u >> 16) & 1u)) >> 16;
}
__device__ __forceinline__ float bflo(u32 u) { return __uint_as_float(u << 16); }
__device__ __forceinline__ float bfhi(u32 u) { return __uint_as_float(u & 0xFFFF0000u); }

// ---------------- CSR build ----------------

__global__ __launch_bounds__(256) void k_count(const int* __restrict__ dst,
                                               int* __restrict__ ideg, int ne) {
  int stride = gridDim.x * blockDim.x;
  for (int e = blockIdx.x * blockDim.x + threadIdx.x; e < ne; e += stride)
    atomicAdd(&ideg[dst[e]], 1);
}

// scan + dinv fused
__global__ __launch_bounds__(1024) void k_scan(const int* __restrict__ ideg,
                                               int* __restrict__ off,
                                               int* __restrict__ cur,
                                               float* __restrict__ dinv, int n) {
  __shared__ int sums[1024];
  int t = threadIdx.x;
  int chunk = (n + 1023) >> 10;
  int s0 = t * chunk;
  int s1 = s0 + chunk;
  if (s0 > n) s0 = n;
  if (s1 > n) s1 = n;
  int tot = 0;
  for (int i = s0; i < s1; ++i) tot += ideg[i];
  sums[t] = tot;
  __syncthreads();
  for (int d = 1; d < 1024; d <<= 1) {
    int v = (t >= d) ? sums[t - d] : 0;
    __syncthreads();
    sums[t] += v;
    __syncthreads();
  }
  int run = (t == 0) ? 0 : sums[t - 1];
  for (int i = s0; i < s1; ++i) {
    off[i] = run;
    cur[i] = run;
    run += ideg[i];
    dinv[i] = rsqrtf((float)ideg[i] + 1.0f);  // +1 = self loop
  }
  if (t == 1023) off[n] = run;
}

__global__ __launch_bounds__(256) void k_fill(const int* __restrict__ src,
                                              const int* __restrict__ dst,
                                              int* __restrict__ cur,
                                              int* __restrict__ csr_src, int ne) {
  int stride = gridDim.x * blockDim.x;
  for (int e = blockIdx.x * blockDim.x + threadIdx.x; e < ne; e += stride) {
    int d = dst[e];
    int s = src[e];
    int p = atomicAdd(&cur[d], 1);
    csr_src[p] = s;
  }
}

// ---------------- W prep: Wt[c][k] bf16-packed, per layer ----------------

__global__ __launch_bounds__(256) void k_wprep(const float* __restrict__ W0,
                                               const float* __restrict__ W1,
                                               const float* __restrict__ W2,
                                               u32* __restrict__ Wt) {
  const float* W = blockIdx.x == 0 ? W0 : (blockIdx.x == 1 ? W1 : W2);
  u32* o = Wt + (size_t)blockIdx.x * DIM * 64;
  int tid = threadIdx.x;
#pragma unroll
  for (int i = 0; i < 32; ++i) {
    int u = tid + i * 256;       // 8192 outputs: Wt[c][kk] = W[2kk][c] | W[2kk+1][c]
    int c = u >> 6;
    int kk = u & 63;
    float lo = W[(size_t)(2 * kk) * DIM + c];
    float hi = W[(size_t)(2 * kk + 1) * DIM + c];
    o[u] = bf16rne(lo) | (bf16rne(hi) << 16);
  }
}

// ---------------- MFMA GEMM: C_bf16[n,128] = dinv[row]*(f(A)[n,128] @ W) ----
// f(A) = relu(A*sc+sh) when sc != null. Wt is bf16-packed W^T (u32[128][64]).

__global__ __launch_bounds__(256) void k_gemm(const float* __restrict__ A,
                                              const u32* __restrict__ Wt,
                                              const float* __restrict__ dinv,
                                              const float* __restrict__ sc,
                                              const float* __restrict__ sh,
                                              u32* __restrict__ C, int n) {
  __shared__ u32 sA[8192];   // 128 rows x 16 slots x 16B, slot-swizzled
  __shared__ u32 sB[8192];   // Wt same layout
  __shared__ float sdv[DIM];
  int tid = threadIdx.x;
  int row0 = blockIdx.x * DIM;

  {
    const uint4* w4 = (const uint4*)Wt;
#pragma unroll
    for (int i = 0; i < 8; ++i) {
      int u = tid + i * 256;
      int r = u >> 4, s = u & 15;
      uint4 v = w4[u];
      ((uint4*)sB)[r * 16 + (s ^ (r & 7))] = v;
    }
  }
#pragma unroll
  for (int i = 0; i < 8; ++i) {
    int u = tid + i * 256;
    int r = u >> 4, s = u & 15;
    int gr = row0 + r;
    uint4 pv = make_uint4(0u, 0u, 0u, 0u);
    if (gr < n) {
      float4 v0 = ((const float4*)A)[(size_t)gr * 32 + s * 2];
      float4 v1 = ((const float4*)A)[(size_t)gr * 32 + s * 2 + 1];
      if (sc) {
        float4 s0 = ((const float4*)sc)[s * 2];
        float4 s1 = ((const float4*)sc)[s * 2 + 1];
        float4 h0 = ((const float4*)sh)[s * 2];
        float4 h1 = ((const float4*)sh)[s * 2 + 1];
        v0.x = fmaxf(fmaf(v0.x, s0.x, h0.x), 0.f);
        v0.y = fmaxf(fmaf(v0.y, s0.y, h0.y), 0.f);
        v0.z = fmaxf(fmaf(v0.z, s0.z, h0.z), 0.f);
        v0.w = fmaxf(fmaf(v0.w, s0.w, h0.w), 0.f);
        v1.x = fmaxf(fmaf(v1.x, s1.x, h1.x), 0.f);
        v1.y = fmaxf(fmaf(v1.y, s1.y, h1.y), 0.f);
        v1.z = fmaxf(fmaf(v1.z, s1.z, h1.z), 0.f);
        v1.w = fmaxf(fmaf(v1.w, s1.w, h1.w), 0.f);
      }
      pv.x = bf16rne(v0.x) | (bf16rne(v0.y) << 16);
      pv.y = bf16rne(v0.z) | (bf16rne(v0.w) << 16);
      pv.z = bf16rne(v1.x) | (bf16rne(v1.y) << 16);
      pv.w = bf16rne(v1.z) | (bf16rne(v1.w) << 16);
    }
    ((uint4*)sA)[r * 16 + (s ^ (r & 7))] = pv;
  }
  if (tid < DIM) sdv[tid] = (row0 + tid < n) ? dinv[row0 + tid] : 0.f;
  __syncthreads();

  int lane = tid & 63;
  int w = tid >> 6;
  int lr = lane & 15;
  int g = lane >> 4;
  f32x4 acc[2][8];
#pragma unroll
  for (int m = 0; m < 2; ++m)
#pragma unroll
    for (int nt = 0; nt < 8; ++nt) acc[m][nt] = (f32x4){0.f, 0.f, 0.f, 0.f};

#pragma unroll
  for (int kc = 0; kc < 4; ++kc) {
    short8 a[2], b[8];
#pragma unroll
    for (int m = 0; m < 2; ++m) {
      int r = w * 32 + m * 16 + lr;
      int sp = (kc * 4 + g) ^ (r & 7);
      a[m] = *(const short8*)&sA[(r * 16 + sp) * 4];
    }
#pragma unroll
    for (int nt = 0; nt < 8; ++nt) {
      int r = nt * 16 + lr;
      int sp = (kc * 4 + g) ^ (r & 7);
      b[nt] = *(const short8*)&sB[(r * 16 + sp) * 4];
    }
#pragma unroll
    for (int m = 0; m < 2; ++m)
#pragma unroll
      for (int nt = 0; nt < 8; ++nt)
        acc[m][nt] = __builtin_amdgcn_mfma_f32_16x16x32_bf16(a[m], b[nt], acc[m][nt], 0, 0, 0);
  }
  __syncthreads();

  {
    unsigned short* so = (unsigned short*)sA;
#pragma unroll
    for (int m = 0; m < 2; ++m) {
#pragma unroll
      for (int nt = 0; nt < 8; ++nt) {
#pragma unroll
        for (int r4 = 0; r4 < 4; ++r4) {
          int rl = w * 32 + m * 16 + g * 4 + r4;
          int col = ((nt ^ ((rl >> 2) & 7)) << 4) + lr;  // 16-col-block swizzle
          so[rl * DIM + col] = (unsigned short)bf16rne(acc[m][nt][r4] * sdv[rl]);
        }
      }
    }
  }
  __syncthreads();
#pragma unroll
  for (int i = 0; i < 8; ++i) {
    int u = tid + i * 256;
    int r = u >> 4, s = u & 15;
    if (row0 + r < n) {
      int sswz = (s & 1) | (((s >> 1) ^ ((r >> 2) & 7)) << 1);
      ((uint4*)C)[(size_t)(row0 + r) * 16 + s] = ((uint4*)sA)[r * 16 + sswz];
    }
  }
}

// ---------------- Aggregation: ONE NODE PER 64-LANE WAVE ----------------
// xw rows bf16-packed (256 B = 64 u32). lane loads 1 u32 = cols [2*lane, 2*lane+1].
// Edge range wave-uniform -> SGPR indices, saddr gathers, zero divergence.
// prev raw pre-BN f32; if psc given, residual = relu(prev*psc+psh).

__global__ __launch_bounds__(256) void k_agg(const u32* __restrict__ xw,
                                             const int* __restrict__ off,
                                             const int* __restrict__ csr_src,
                                             const float* __restrict__ dinv,
                                             const float* __restrict__ bias,
                                             const float* __restrict__ prev,
                                             const float* __restrict__ psc,
                                             const float* __restrict__ psh,
                                             float* __restrict__ out,
                                             float* __restrict__ ssum,
                                             float* __restrict__ ssq, int n) {
  int tid = threadIdx.x;
  int lane = tid & 63;
  int wave = tid >> 6;  // 4 node slots per block
  float2 bc = ((const float2*)bias)[lane];
  float2 ps, ph;
  if (psc) {
    ps = ((const float2*)psc)[lane];
    ph = ((const float2*)psh)[lane];
  }
  float s0 = 0.f, s1 = 0.f, q0 = 0.f, q1 = 0.f;
  int stride = gridDim.x * 4;

  for (int node = blockIdx.x * 4 + wave; node < n; node += stride) {
    int e0 = __builtin_amdgcn_readfirstlane(off[node]);
    int e1 = __builtin_amdgcn_readfirstlane(off[node + 1]);
    float a0, a1;
    {
      u32 s = xw[(size_t)node * 64 + lane];  // self loop (pre-scaled)
      a0 = bflo(s);
      a1 = bfhi(s);
    }
    int e = e0;
    for (; e + 8 <= e1; e += 8) {
      int i0 = __builtin_amdgcn_readfirstlane(csr_src[e]);
      int i1 = __builtin_amdgcn_readfirstlane(csr_src[e + 1]);
      int i2 = __builtin_amdgcn_readfirstlane(csr_src[e + 2]);
      int i3 = __builtin_amdgcn_readfirstlane(csr_src[e + 3]);
      int i4 = __builtin_amdgcn_readfirstlane(csr_src[e + 4]);
      int i5 = __builtin_amdgcn_readfirstlane(csr_src[e + 5]);
      int i6 = __builtin_amdgcn_readfirstlane(csr_src[e + 6]);
      int i7 = __builtin_amdgcn_readfirstlane(csr_src[e + 7]);
      u32 v0 = xw[(size_t)i0 * 64 + lane];
      u32 v1 = xw[(size_t)i1 * 64 + lane];
      u32 v2 = xw[(size_t)i2 * 64 + lane];
      u32 v3 = xw[(size_t)i3 * 64 + lane];
      u32 v4 = xw[(size_t)i4 * 64 + lane];
      u32 v5 = xw[(size_t)i5 * 64 + lane];
      u32 v6 = xw[(size_t)i6 * 64 + lane];
      u32 v7 = xw[(size_t)i7 * 64 + lane];
      a0 += ((bflo(v0) + bflo(v1)) + (bflo(v2) + bflo(v3))) +
            ((bflo(v4) + bflo(v5)) + (bflo(v6) + bflo(v7)));
      a1 += ((bfhi(v0) + bfhi(v1)) + (bfhi(v2) + bfhi(v3))) +
            ((bfhi(v4) + bfhi(v5)) + (bfhi(v6) + bfhi(v7)));
    }
    for (; e + 4 <= e1; e += 4) {
      int i0 = __builtin_amdgcn_readfirstlane(csr_src[e]);
      int i1 = __builtin_amdgcn_readfirstlane(csr_src[e + 1]);
      int i2 = __builtin_amdgcn_readfirstlane(csr_src[e + 2]);
      int i3 = __builtin_amdgcn_readfirstlane(csr_src[e + 3]);
      u32 v0 = xw[(size_t)i0 * 64 + lane];
      u32 v1 = xw[(size_t)i1 * 64 + lane];
      u32 v2 = xw[(size_t)i2 * 64 + lane];
      u32 v3 = xw[(size_t)i3 * 64 + lane];
      a0 += (bflo(v0) + bflo(v1)) + (bflo(v2) + bflo(v3));
      a1 += (bfhi(v0) + bfhi(v1)) + (bfhi(v2) + bfhi(v3));
    }
    for (; e < e1; ++e) {
      int i0 = __builtin_amdgcn_readfirstlane(csr_src[e]);
      u32 v = xw[(size_t)i0 * 64 + lane];
      a0 += bflo(v);
      a1 += bfhi(v);
    }
    float di = dinv[node];
    float v0 = fmaf(di, a0, bc.x);
    float v1 = fmaf(di, a1, bc.y);
    if (prev) {
      float2 pv = ((const float2*)prev)[(size_t)node * 64 + lane];
      if (psc) {
        pv.x = fmaxf(fmaf(pv.x, ps.x, ph.x), 0.f);
        pv.y = fmaxf(fmaf(pv.y, ps.y, ph.y), 0.f);
      }
      v0 += pv.x;
      v1 += pv.y;
    }
    ((float2*)out)[(size_t)node * 64 + lane] = make_float2(v0, v1);
    s0 += v0;
    s1 += v1;
    q0 = fmaf(v0, v0, q0);
    q1 = fmaf(v1, v1, q1);
  }

  __shared__ float red[4][64][2];
  red[wave][lane][0] = s0;
  red[wave][lane][1] = s1;
  __syncthreads();
  if (wave == 0) {
    float t0 = (red[0][lane][0] + red[1][lane][0]) + (red[2][lane][0] + red[3][lane][0]);
    float t1 = (red[0][lane][1] + red[1][lane][1]) + (red[2][lane][1] + red[3][lane][1]);
    atomicAdd(&ssum[lane * 2], t0);
    atomicAdd(&ssum[lane * 2 + 1], t1);
  }
  __syncthreads();
  red[wave][lane][0] = q0;
  red[wave][lane][1] = q1;
  __syncthreads();
  if (wave == 0) {
    float t0 = (red[0][lane][0] + red[1][lane][0]) + (red[2][lane][0] + red[3][lane][0]);
    float t1 = (red[0][lane][1] + red[1][lane][1]) + (red[2][lane][1] + red[3][lane][1]);
    atomicAdd(&ssq[lane * 2], t0);
    atomicAdd(&ssq[lane * 2 + 1], t1);
  }
}

// ---------------- BN finalize + final normalize/relu ----------------

__global__ void k_bn(const float* __restrict__ ssum, const float* __restrict__ ssq,
                     const float* __restrict__ gamma, const float* __restrict__ beta,
                     float* __restrict__ scale, float* __restrict__ shift, float invn) {
  int c = threadIdx.x;
  float mu = ssum[c] * invn;
  float var = ssq[c] * invn - mu * mu;
  float rstd = rsqrtf(var + BN_EPS);
  float s = rstd * gamma[c];
  scale[c] = s;
  shift[c] = beta[c] - mu * s;
}

__global__ __launch_bounds__(256) void k_norm(const float* __restrict__ in,
                                              float* __restrict__ out,
                                              const float* __restrict__ scale,
                                              const float* __restrict__ shift, int n4) {
  int stride = gridDim.x * blockDim.x;
  for (int i = blockIdx.x * blockDim.x + threadIdx.x; i < n4; i += stride) {
    int cg = i & 31;
    float4 sc = ((const float4*)scale)[cg];
    float4 sh = ((const float4*)shift)[cg];
    float4 v = ((const float4*)in)[i];
    v.x = fmaxf(fmaf(v.x, sc.x, sh.x), 0.f);
    v.y = fmaxf(fmaf(v.y, sc.y, sh.y), 0.f);
    v.z = fmaxf(fmaf(v.z, sc.z, sh.z), 0.f);
    v.w = fmaxf(fmaf(v.w, sc.w, sh.w), 0.f);
    ((float4*)out)[i] = v;
  }
}

// ---------------- launch ----------------

extern "C" void kernel_launch(void* const* d_in, const int* in_sizes, int n_in,
                              void* d_out, int out_size, void* d_ws, size_t ws_size,
                              hipStream_t stream) {
  const float* x = (const float*)d_in[0];
  const int* ei = (const int*)d_in[1];
  int n = in_sizes[0] / DIM;   // 100000
  int ne = in_sizes[1] / 2;    // 1600000
  const int* src = ei;
  const int* dst = ei + ne;

  const float *W[3], *B[3], *G[3], *Bt[3];
  if (n_in >= 14) {
    for (int l = 0; l < 3; ++l) {
      W[l] = (const float*)d_in[2 + l];
      B[l] = (const float*)d_in[5 + l];
      G[l] = (const float*)d_in[8 + l];
      Bt[l] = (const float*)d_in[11 + l];
    }
  } else {
    for (int l = 0; l < 3; ++l) {
      W[l] = (const float*)d_in[2] + (size_t)l * DIM * DIM;
      B[l] = (const float*)d_in[3] + (size_t)l * DIM;
      G[l] = (const float*)d_in[4] + (size_t)l * DIM;
      Bt[l] = (const float*)d_in[5] + (size_t)l * DIM;
    }
  }

  float* out = (float*)d_out;

  char* p = (char*)d_ws;
  auto carve = [&](size_t bytes) {
    void* q = (void*)p;
    p += (bytes + 255) & ~(size_t)255;
    return q;
  };
  int* ideg = (int*)carve((size_t)n * 4);
  int* coff = (int*)carve((size_t)(n + 1) * 4);
  int* cur = (int*)carve((size_t)n * 4);
  float* dinv = (float*)carve((size_t)n * 4);
  int* csr_src = (int*)carve((size_t)ne * 4);
  u32* xw = (u32*)carve((size_t)n * DIM * 2);   // bf16 packed
  float* buf1 = (float*)carve((size_t)n * DIM * 4);
  u32* wt = (u32*)carve(3 * DIM * 64 * 4);      // bf16-packed W^T x3
  float* stats = (float*)carve(3 * 256 * 4);
  float* scsh = (float*)carve(3 * 256 * 4);

  hipMemsetAsync(ideg, 0, (size_t)n * 4, stream);
  hipMemsetAsync(stats, 0, 3 * 256 * 4, stream);

  k_wprep<<<3, 256, 0, stream>>>(W[0], W[1], W[2], wt);
  k_count<<<1024, 256, 0, stream>>>(dst, ideg, ne);
  k_scan<<<1, 1024, 0, stream>>>(ideg, coff, cur, dinv, n);
  k_fill<<<1024, 256, 0, stream>>>(src, dst, cur, csr_src, ne);

  float invn = 1.0f / (float)n;
  int nblk = (n + DIM - 1) / DIM;
  const int AGG_GRID = 2048;   // proven best (R6/R7); 4096 regressed (R9)

  // layer 0
  float* ss0 = stats;         float* sc0 = scsh;
  k_gemm<<<nblk, 256, 0, stream>>>(x, wt, dinv, nullptr, nullptr, xw, n);
  k_agg<<<AGG_GRID, 256, 0, stream>>>(xw, coff, csr_src, dinv, B[0], nullptr, nullptr, nullptr,
                                      buf1, ss0, ss0 + 128, n);
  k_bn<<<1, 128, 0, stream>>>(ss0, ss0 + 128, G[0], Bt[0], sc0, sc0 + 128, invn);

  // layer 1
  float* ss1 = stats + 256;   float* sc1 = scsh + 256;
  k_gemm<<<nblk, 256, 0, stream>>>(buf1, wt + (size_t)DIM * 64, dinv, sc0, sc0 + 128, xw, n);
  k_agg<<<AGG_GRID, 256, 0, stream>>>(xw, coff, csr_src, dinv, B[1], buf1, sc0, sc0 + 128,
                                      out, ss1, ss1 + 128, n);
  k_bn<<<1, 128, 0, stream>>>(ss1, ss1 + 128, G[1], Bt[1], sc1, sc1 + 128, invn);

  // layer 2
  float* ss2 = stats + 512;   float* sc2 = scsh + 512;
  k_gemm<<<nblk, 256, 0, stream>>>(out, wt + (size_t)2 * DIM * 64, dinv, sc1, sc1 + 128, xw, n);
  k_agg<<<AGG_GRID, 256, 0, stream>>>(xw, coff, csr_src, dinv, B[2], out, sc1, sc1 + 128,
                                      buf1, ss2, ss2 + 128, n);
  k_bn<<<1, 128, 0, stream>>>(ss2, ss2 + 128, G[2], Bt[2], sc2, sc2 + 128, invn);

  // final normalize into d_out
  k_norm<<<2048, 256, 0, stream>>>(buf1, out, sc2, sc2 + 128, n * DIM / 4);
}

// Round 11
// 774.676 us; speedup vs baseline: 2.3707x; 1.3378x over previous
//
#include <hip/hip_runtime.h>

#define DIM 128
#define BN_EPS 1e-5f
#define SCAN_BS 512
typedef unsigned int u32;
typedef __attribute__((ext_vector_type(8))) short short8;
typedef __attribute__((ext_vector_type(4))) float f32x4;

__device__ __forceinline__ u32 bf16rne(float x) {
  u32 u = __float_as_uint(x);
  return (u + 0x7FFFu + ((u >> 16) & 1u)) >> 16;
}
__device__ __forceinline__ float bflo(u32 u) { return __uint_as_float(u << 16); }
__device__ __forceinline__ float bfhi(u32 u) { return __uint_as_float(u & 0xFFFF0000u); }

// ---------------- CSR build ----------------

__global__ __launch_bounds__(256) void k_count(const int* __restrict__ dst,
                                               int* __restrict__ ideg, int ne) {
  int stride = gridDim.x * blockDim.x;
  for (int e = blockIdx.x * blockDim.x + threadIdx.x; e < ne; e += stride)
    atomicAdd(&ideg[dst[e]], 1);
}

// device-wide scan, 3 passes (chunk = SCAN_BS elements per block)

__global__ __launch_bounds__(SCAN_BS) void k_scan1(const int* __restrict__ ideg,
                                                   int* __restrict__ bsum, int n) {
  __shared__ int red[SCAN_BS];
  int t = threadIdx.x;
  int i = blockIdx.x * SCAN_BS + t;
  red[t] = (i < n) ? ideg[i] : 0;
  __syncthreads();
  for (int d = SCAN_BS / 2; d > 0; d >>= 1) {
    if (t < d) red[t] += red[t + d];
    __syncthreads();
  }
  if (t == 0) bsum[blockIdx.x] = red[0];
}

__global__ __launch_bounds__(256) void k_scan2(const int* __restrict__ bsum,
                                               int* __restrict__ bbase, int nb,
                                               int* __restrict__ off, int n, int ne) {
  __shared__ int s[256];
  int t = threadIdx.x;
  s[t] = (t < nb) ? bsum[t] : 0;
  __syncthreads();
  for (int d = 1; d < 256; d <<= 1) {
    int v = (t >= d) ? s[t - d] : 0;
    __syncthreads();
    s[t] += v;
    __syncthreads();
  }
  if (t < nb) bbase[t] = (t == 0) ? 0 : s[t - 1];
  if (t == 0) off[n] = ne;  // total degree == ne (every edge counted once at dst)
}

__global__ __launch_bounds__(SCAN_BS) void k_scan3(const int* __restrict__ ideg,
                                                   const int* __restrict__ bbase,
                                                   int* __restrict__ off,
                                                   int* __restrict__ cur,
                                                   float* __restrict__ dinv, int n) {
  __shared__ int s[SCAN_BS];
  int t = threadIdx.x;
  int i = blockIdx.x * SCAN_BS + t;
  int v = (i < n) ? ideg[i] : 0;
  s[t] = v;
  __syncthreads();
  for (int d = 1; d < SCAN_BS; d <<= 1) {
    int u = (t >= d) ? s[t - d] : 0;
    __syncthreads();
    s[t] += u;
    __syncthreads();
  }
  if (i < n) {
    int excl = bbase[blockIdx.x] + s[t] - v;
    off[i] = excl;
    cur[i] = excl;
    dinv[i] = rsqrtf((float)v + 1.0f);  // +1 = self loop
  }
}

__global__ __launch_bounds__(256) void k_fill(const int* __restrict__ src,
                                              const int* __restrict__ dst,
                                              int* __restrict__ cur,
                                              int* __restrict__ csr_src, int ne) {
  int stride = gridDim.x * blockDim.x;
  for (int e = blockIdx.x * blockDim.x + threadIdx.x; e < ne; e += stride) {
    int d = dst[e];
    int s = src[e];
    int p = atomicAdd(&cur[d], 1);
    csr_src[p] = s;
  }
}

// ---------------- W prep: Wt[c][k] bf16-packed, per layer ----------------

__global__ __launch_bounds__(256) void k_wprep(const float* __restrict__ W0,
                                               const float* __restrict__ W1,
                                               const float* __restrict__ W2,
                                               u32* __restrict__ Wt) {
  const float* W = blockIdx.x == 0 ? W0 : (blockIdx.x == 1 ? W1 : W2);
  u32* o = Wt + (size_t)blockIdx.x * DIM * 64;
  int tid = threadIdx.x;
#pragma unroll
  for (int i = 0; i < 32; ++i) {
    int u = tid + i * 256;       // 8192 outputs: Wt[c][kk] = W[2kk][c] | W[2kk+1][c]
    int c = u >> 6;
    int kk = u & 63;
    float lo = W[(size_t)(2 * kk) * DIM + c];
    float hi = W[(size_t)(2 * kk + 1) * DIM + c];
    o[u] = bf16rne(lo) | (bf16rne(hi) << 16);
  }
}

// ---------------- MFMA GEMM: C_bf16[n,128] = dinv[row]*(f(A)[n,128] @ W) ----
// f(A) = relu(A*sc+sh) when sc != null. Wt is bf16-packed W^T (u32[128][64]).

__global__ __launch_bounds__(256) void k_gemm(const float* __restrict__ A,
                                              const u32* __restrict__ Wt,
                                              const float* __restrict__ dinv,
                                              const float* __restrict__ sc,
                                              const float* __restrict__ sh,
                                              u32* __restrict__ C, int n) {
  __shared__ u32 sA[8192];   // 128 rows x 16 slots x 16B, slot-swizzled
  __shared__ u32 sB[8192];   // Wt same layout
  __shared__ float sdv[DIM];
  int tid = threadIdx.x;
  int row0 = blockIdx.x * DIM;

  {
    const uint4* w4 = (const uint4*)Wt;
#pragma unroll
    for (int i = 0; i < 8; ++i) {
      int u = tid + i * 256;
      int r = u >> 4, s = u & 15;
      uint4 v = w4[u];
      ((uint4*)sB)[r * 16 + (s ^ (r & 7))] = v;
    }
  }
#pragma unroll
  for (int i = 0; i < 8; ++i) {
    int u = tid + i * 256;
    int r = u >> 4, s = u & 15;
    int gr = row0 + r;
    uint4 pv = make_uint4(0u, 0u, 0u, 0u);
    if (gr < n) {
      float4 v0 = ((const float4*)A)[(size_t)gr * 32 + s * 2];
      float4 v1 = ((const float4*)A)[(size_t)gr * 32 + s * 2 + 1];
      if (sc) {
        float4 s0 = ((const float4*)sc)[s * 2];
        float4 s1 = ((const float4*)sc)[s * 2 + 1];
        float4 h0 = ((const float4*)sh)[s * 2];
        float4 h1 = ((const float4*)sh)[s * 2 + 1];
        v0.x = fmaxf(fmaf(v0.x, s0.x, h0.x), 0.f);
        v0.y = fmaxf(fmaf(v0.y, s0.y, h0.y), 0.f);
        v0.z = fmaxf(fmaf(v0.z, s0.z, h0.z), 0.f);
        v0.w = fmaxf(fmaf(v0.w, s0.w, h0.w), 0.f);
        v1.x = fmaxf(fmaf(v1.x, s1.x, h1.x), 0.f);
        v1.y = fmaxf(fmaf(v1.y, s1.y, h1.y), 0.f);
        v1.z = fmaxf(fmaf(v1.z, s1.z, h1.z), 0.f);
        v1.w = fmaxf(fmaf(v1.w, s1.w, h1.w), 0.f);
      }
      pv.x = bf16rne(v0.x) | (bf16rne(v0.y) << 16);
      pv.y = bf16rne(v0.z) | (bf16rne(v0.w) << 16);
      pv.z = bf16rne(v1.x) | (bf16rne(v1.y) << 16);
      pv.w = bf16rne(v1.z) | (bf16rne(v1.w) << 16);
    }
    ((uint4*)sA)[r * 16 + (s ^ (r & 7))] = pv;
  }
  if (tid < DIM) sdv[tid] = (row0 + tid < n) ? dinv[row0 + tid] : 0.f;
  __syncthreads();

  int lane = tid & 63;
  int w = tid >> 6;
  int lr = lane & 15;
  int g = lane >> 4;
  f32x4 acc[2][8];
#pragma unroll
  for (int m = 0; m < 2; ++m)
#pragma unroll
    for (int nt = 0; nt < 8; ++nt) acc[m][nt] = (f32x4){0.f, 0.f, 0.f, 0.f};

#pragma unroll
  for (int kc = 0; kc < 4; ++kc) {
    short8 a[2], b[8];
#pragma unroll
    for (int m = 0; m < 2; ++m) {
      int r = w * 32 + m * 16 + lr;
      int sp = (kc * 4 + g) ^ (r & 7);
      a[m] = *(const short8*)&sA[(r * 16 + sp) * 4];
    }
#pragma unroll
    for (int nt = 0; nt < 8; ++nt) {
      int r = nt * 16 + lr;
      int sp = (kc * 4 + g) ^ (r & 7);
      b[nt] = *(const short8*)&sB[(r * 16 + sp) * 4];
    }
#pragma unroll
    for (int m = 0; m < 2; ++m)
#pragma unroll
      for (int nt = 0; nt < 8; ++nt)
        acc[m][nt] = __builtin_amdgcn_mfma_f32_16x16x32_bf16(a[m], b[nt], acc[m][nt], 0, 0, 0);
  }
  __syncthreads();

  {
    unsigned short* so = (unsigned short*)sA;
#pragma unroll
    for (int m = 0; m < 2; ++m) {
#pragma unroll
      for (int nt = 0; nt < 8; ++nt) {
#pragma unroll
        for (int r4 = 0; r4 < 4; ++r4) {
          int rl = w * 32 + m * 16 + g * 4 + r4;
          int col = ((nt ^ ((rl >> 2) & 7)) << 4) + lr;  // 16-col-block swizzle
          so[rl * DIM + col] = (unsigned short)bf16rne(acc[m][nt][r4] * sdv[rl]);
        }
      }
    }
  }
  __syncthreads();
#pragma unroll
  for (int i = 0; i < 8; ++i) {
    int u = tid + i * 256;
    int r = u >> 4, s = u & 15;
    if (row0 + r < n) {
      int sswz = (s & 1) | (((s >> 1) ^ ((r >> 2) & 7)) << 1);
      ((uint4*)C)[(size_t)(row0 + r) * 16 + s] = ((uint4*)sA)[r * 16 + sswz];
    }
  }
}

// ---------------- Aggregation: ONE NODE PER 64-LANE WAVE (proven R10) ----------------

__global__ __launch_bounds__(256) void k_agg(const u32* __restrict__ xw,
                                             const int* __restrict__ off,
                                             const int* __restrict__ csr_src,
                                             const float* __restrict__ dinv,
                                             const float* __restrict__ bias,
                                             const float* __restrict__ prev,
                                             const float* __restrict__ psc,
                                             const float* __restrict__ psh,
                                             float* __restrict__ out,
                                             float* __restrict__ ssum,
                                             float* __restrict__ ssq, int n) {
  int tid = threadIdx.x;
  int lane = tid & 63;
  int wave = tid >> 6;  // 4 node slots per block
  float2 bc = ((const float2*)bias)[lane];
  float2 ps, ph;
  if (psc) {
    ps = ((const float2*)psc)[lane];
    ph = ((const float2*)psh)[lane];
  }
  float s0 = 0.f, s1 = 0.f, q0 = 0.f, q1 = 0.f;
  int stride = gridDim.x * 4;

  for (int node = blockIdx.x * 4 + wave; node < n; node += stride) {
    int e0 = __builtin_amdgcn_readfirstlane(off[node]);
    int e1 = __builtin_amdgcn_readfirstlane(off[node + 1]);
    float a0, a1;
    {
      u32 s = xw[(size_t)node * 64 + lane];  // self loop (pre-scaled)
      a0 = bflo(s);
      a1 = bfhi(s);
    }
    int e = e0;
    for (; e + 8 <= e1; e += 8) {
      int i0 = __builtin_amdgcn_readfirstlane(csr_src[e]);
      int i1 = __builtin_amdgcn_readfirstlane(csr_src[e + 1]);
      int i2 = __builtin_amdgcn_readfirstlane(csr_src[e + 2]);
      int i3 = __builtin_amdgcn_readfirstlane(csr_src[e + 3]);
      int i4 = __builtin_amdgcn_readfirstlane(csr_src[e + 4]);
      int i5 = __builtin_amdgcn_readfirstlane(csr_src[e + 5]);
      int i6 = __builtin_amdgcn_readfirstlane(csr_src[e + 6]);
      int i7 = __builtin_amdgcn_readfirstlane(csr_src[e + 7]);
      u32 v0 = xw[(size_t)i0 * 64 + lane];
      u32 v1 = xw[(size_t)i1 * 64 + lane];
      u32 v2 = xw[(size_t)i2 * 64 + lane];
      u32 v3 = xw[(size_t)i3 * 64 + lane];
      u32 v4 = xw[(size_t)i4 * 64 + lane];
      u32 v5 = xw[(size_t)i5 * 64 + lane];
      u32 v6 = xw[(size_t)i6 * 64 + lane];
      u32 v7 = xw[(size_t)i7 * 64 + lane];
      a0 += ((bflo(v0) + bflo(v1)) + (bflo(v2) + bflo(v3))) +
            ((bflo(v4) + bflo(v5)) + (bflo(v6) + bflo(v7)));
      a1 += ((bfhi(v0) + bfhi(v1)) + (bfhi(v2) + bfhi(v3))) +
            ((bfhi(v4) + bfhi(v5)) + (bfhi(v6) + bfhi(v7)));
    }
    for (; e + 4 <= e1; e += 4) {
      int i0 = __builtin_amdgcn_readfirstlane(csr_src[e]);
      int i1 = __builtin_amdgcn_readfirstlane(csr_src[e + 1]);
      int i2 = __builtin_amdgcn_readfirstlane(csr_src[e + 2]);
      int i3 = __builtin_amdgcn_readfirstlane(csr_src[e + 3]);
      u32 v0 = xw[(size_t)i0 * 64 + lane];
      u32 v1 = xw[(size_t)i1 * 64 + lane];
      u32 v2 = xw[(size_t)i2 * 64 + lane];
      u32 v3 = xw[(size_t)i3 * 64 + lane];
      a0 += (bflo(v0) + bflo(v1)) + (bflo(v2) + bflo(v3));
      a1 += (bfhi(v0) + bfhi(v1)) + (bfhi(v2) + bfhi(v3));
    }
    for (; e < e1; ++e) {
      int i0 = __builtin_amdgcn_readfirstlane(csr_src[e]);
      u32 v = xw[(size_t)i0 * 64 + lane];
      a0 += bflo(v);
      a1 += bfhi(v);
    }
    float di = dinv[node];
    float v0 = fmaf(di, a0, bc.x);
    float v1 = fmaf(di, a1, bc.y);
    if (prev) {
      float2 pv = ((const float2*)prev)[(size_t)node * 64 + lane];
      if (psc) {
        pv.x = fmaxf(fmaf(pv.x, ps.x, ph.x), 0.f);
        pv.y = fmaxf(fmaf(pv.y, ps.y, ph.y), 0.f);
      }
      v0 += pv.x;
      v1 += pv.y;
    }
    ((float2*)out)[(size_t)node * 64 + lane] = make_float2(v0, v1);
    s0 += v0;
    s1 += v1;
    q0 = fmaf(v0, v0, q0);
    q1 = fmaf(v1, v1, q1);
  }

  __shared__ float red[4][64][2];
  red[wave][lane][0] = s0;
  red[wave][lane][1] = s1;
  __syncthreads();
  if (wave == 0) {
    float t0 = (red[0][lane][0] + red[1][lane][0]) + (red[2][lane][0] + red[3][lane][0]);
    float t1 = (red[0][lane][1] + red[1][lane][1]) + (red[2][lane][1] + red[3][lane][1]);
    atomicAdd(&ssum[lane * 2], t0);
    atomicAdd(&ssum[lane * 2 + 1], t1);
  }
  __syncthreads();
  red[wave][lane][0] = q0;
  red[wave][lane][1] = q1;
  __syncthreads();
  if (wave == 0) {
    float t0 = (red[0][lane][0] + red[1][lane][0]) + (red[2][lane][0] + red[3][lane][0]);
    float t1 = (red[0][lane][1] + red[1][lane][1]) + (red[2][lane][1] + red[3][lane][1]);
    atomicAdd(&ssq[lane * 2], t0);
    atomicAdd(&ssq[lane * 2 + 1], t1);
  }
}

// ---------------- BN finalize + final normalize/relu ----------------

__global__ void k_bn(const float* __restrict__ ssum, const float* __restrict__ ssq,
                     const float* __restrict__ gamma, const float* __restrict__ beta,
                     float* __restrict__ scale, float* __restrict__ shift, float invn) {
  int c = threadIdx.x;
  float mu = ssum[c] * invn;
  float var = ssq[c] * invn - mu * mu;
  float rstd = rsqrtf(var + BN_EPS);
  float s = rstd * gamma[c];
  scale[c] = s;
  shift[c] = beta[c] - mu * s;
}

__global__ __launch_bounds__(256) void k_norm(const float* __restrict__ in,
                                              float* __restrict__ out,
                                              const float* __restrict__ scale,
                                              const float* __restrict__ shift, int n4) {
  int stride = gridDim.x * blockDim.x;
  for (int i = blockIdx.x * blockDim.x + threadIdx.x; i < n4; i += stride) {
    int cg = i & 31;
    float4 sc = ((const float4*)scale)[cg];
    float4 sh = ((const float4*)shift)[cg];
    float4 v = ((const float4*)in)[i];
    v.x = fmaxf(fmaf(v.x, sc.x, sh.x), 0.f);
    v.y = fmaxf(fmaf(v.y, sc.y, sh.y), 0.f);
    v.z = fmaxf(fmaf(v.z, sc.z, sh.z), 0.f);
    v.w = fmaxf(fmaf(v.w, sc.w, sh.w), 0.f);
    ((float4*)out)[i] = v;
  }
}

// ---------------- launch ----------------

extern "C" void kernel_launch(void* const* d_in, const int* in_sizes, int n_in,
                              void* d_out, int out_size, void* d_ws, size_t ws_size,
                              hipStream_t stream) {
  const float* x = (const float*)d_in[0];
  const int* ei = (const int*)d_in[1];
  int n = in_sizes[0] / DIM;   // 100000
  int ne = in_sizes[1] / 2;    // 1600000
  const int* src = ei;
  const int* dst = ei + ne;

  const float *W[3], *B[3], *G[3], *Bt[3];
  if (n_in >= 14) {
    for (int l = 0; l < 3; ++l) {
      W[l] = (const float*)d_in[2 + l];
      B[l] = (const float*)d_in[5 + l];
      G[l] = (const float*)d_in[8 + l];
      Bt[l] = (const float*)d_in[11 + l];
    }
  } else {
    for (int l = 0; l < 3; ++l) {
      W[l] = (const float*)d_in[2] + (size_t)l * DIM * DIM;
      B[l] = (const float*)d_in[3] + (size_t)l * DIM;
      G[l] = (const float*)d_in[4] + (size_t)l * DIM;
      Bt[l] = (const float*)d_in[5] + (size_t)l * DIM;
    }
  }

  float* out = (float*)d_out;

  char* p = (char*)d_ws;
  auto carve = [&](size_t bytes) {
    void* q = (void*)p;
    p += (bytes + 255) & ~(size_t)255;
    return q;
  };
  int* ideg = (int*)carve((size_t)n * 4);
  int* coff = (int*)carve((size_t)(n + 1) * 4);
  int* cur = (int*)carve((size_t)n * 4);
  float* dinv = (float*)carve((size_t)n * 4);
  int* csr_src = (int*)carve((size_t)ne * 4);
  u32* xw = (u32*)carve((size_t)n * DIM * 2);   // bf16 packed
  float* buf1 = (float*)carve((size_t)n * DIM * 4);
  u32* wt = (u32*)carve(3 * DIM * 64 * 4);      // bf16-packed W^T x3
  float* stats = (float*)carve(3 * 256 * 4);
  float* scsh = (float*)carve(3 * 256 * 4);
  int* bsum = (int*)carve(256 * 4);
  int* bbase = (int*)carve(256 * 4);

  hipMemsetAsync(ideg, 0, (size_t)n * 4, stream);
  hipMemsetAsync(stats, 0, 3 * 256 * 4, stream);

  int nscan = (n + SCAN_BS - 1) / SCAN_BS;   // 196 <= 256

  k_wprep<<<3, 256, 0, stream>>>(W[0], W[1], W[2], wt);
  k_count<<<1024, 256, 0, stream>>>(dst, ideg, ne);
  k_scan1<<<nscan, SCAN_BS, 0, stream>>>(ideg, bsum, n);
  k_scan2<<<1, 256, 0, stream>>>(bsum, bbase, nscan, coff, n, ne);
  k_scan3<<<nscan, SCAN_BS, 0, stream>>>(ideg, bbase, coff, cur, dinv, n);
  k_fill<<<1024, 256, 0, stream>>>(src, dst, cur, csr_src, ne);

  float invn = 1.0f / (float)n;
  int nblk = (n + DIM - 1) / DIM;
  const int AGG_GRID = 2048;   // proven best (R6/R7); 4096 regressed (R9)

  // layer 0
  float* ss0 = stats;         float* sc0 = scsh;
  k_gemm<<<nblk, 256, 0, stream>>>(x, wt, dinv, nullptr, nullptr, xw, n);
  k_agg<<<AGG_GRID, 256, 0, stream>>>(xw, coff, csr_src, dinv, B[0], nullptr, nullptr, nullptr,
                                      buf1, ss0, ss0 + 128, n);
  k_bn<<<1, 128, 0, stream>>>(ss0, ss0 + 128, G[0], Bt[0], sc0, sc0 + 128, invn);

  // layer 1
  float* ss1 = stats + 256;   float* sc1 = scsh + 256;
  k_gemm<<<nblk, 256, 0, stream>>>(buf1, wt + (size_t)DIM * 64, dinv, sc0, sc0 + 128, xw, n);
  k_agg<<<AGG_GRID, 256, 0, stream>>>(xw, coff, csr_src, dinv, B[1], buf1, sc0, sc0 + 128,
                                      out, ss1, ss1 + 128, n);
  k_bn<<<1, 128, 0, stream>>>(ss1, ss1 + 128, G[1], Bt[1], sc1, sc1 + 128, invn);

  // layer 2
  float* ss2 = stats + 512;   float* sc2 = scsh + 512;
  k_gemm<<<nblk, 256, 0, stream>>>(out, wt + (size_t)2 * DIM * 64, dinv, sc1, sc1 + 128, xw, n);
  k_agg<<<AGG_GRID, 256, 0, stream>>>(xw, coff, csr_src, dinv, B[2], out, sc1, sc1 + 128,
                                      buf1, ss2, ss2 + 128, n);
  k_bn<<<1, 128, 0, stream>>>(ss2, ss2 + 128, G[2], Bt[2], sc2, sc2 + 128, invn);

  // final normalize into d_out
  k_norm<<<2048, 256, 0, stream>>>(buf1, out, sc2, sc2 + 128, n * DIM / 4);
}

// Round 12
// 758.847 us; speedup vs baseline: 2.4201x; 1.0209x over previous
//
#include <hip/hip_runtime.h>

#define DIM 128
#define BN_EPS 1e-5f
#define SCAN_BS 512
typedef unsigned int u32;
typedef __attribute__((ext_vector_type(8))) short short8;
typedef __attribute__((ext_vector_type(4))) float f32x4;

__device__ __forceinline__ u32 bf16rne(float x) {
  u32 u = __float_as_uint(x);
  return (u + 0x7FFFu + ((u >> 16) & 1u)) >> 16;
}
__device__ __forceinline__ float bflo(u32 u) { return __uint_as_float(u << 16); }
__device__ __forceinline__ float bfhi(u32 u) { return __uint_as_float(u & 0xFFFF0000u); }
__device__ __forceinline__ u32 pk(float a, float b) { return bf16rne(a) | (bf16rne(b) << 16); }

// ---------------- CSR build ----------------

__global__ __launch_bounds__(256) void k_count(const int* __restrict__ dst,
                                               int* __restrict__ ideg, int ne) {
  int stride = gridDim.x * blockDim.x;
  for (int e = blockIdx.x * blockDim.x + threadIdx.x; e < ne; e += stride)
    atomicAdd(&ideg[dst[e]], 1);
}

__global__ __launch_bounds__(SCAN_BS) void k_scan1(const int* __restrict__ ideg,
                                                   int* __restrict__ bsum, int n) {
  __shared__ int red[SCAN_BS];
  int t = threadIdx.x;
  int i = blockIdx.x * SCAN_BS + t;
  red[t] = (i < n) ? ideg[i] : 0;
  __syncthreads();
  for (int d = SCAN_BS / 2; d > 0; d >>= 1) {
    if (t < d) red[t] += red[t + d];
    __syncthreads();
  }
  if (t == 0) bsum[blockIdx.x] = red[0];
}

__global__ __launch_bounds__(256) void k_scan2(const int* __restrict__ bsum,
                                               int* __restrict__ bbase, int nb,
                                               int* __restrict__ off, int n, int ne) {
  __shared__ int s[256];
  int t = threadIdx.x;
  s[t] = (t < nb) ? bsum[t] : 0;
  __syncthreads();
  for (int d = 1; d < 256; d <<= 1) {
    int v = (t >= d) ? s[t - d] : 0;
    __syncthreads();
    s[t] += v;
    __syncthreads();
  }
  if (t < nb) bbase[t] = (t == 0) ? 0 : s[t - 1];
  if (t == 0) off[n] = ne;
}

__global__ __launch_bounds__(SCAN_BS) void k_scan3(const int* __restrict__ ideg,
                                                   const int* __restrict__ bbase,
                                                   int* __restrict__ off,
                                                   int* __restrict__ cur,
                                                   float* __restrict__ dinv, int n) {
  __shared__ int s[SCAN_BS];
  int t = threadIdx.x;
  int i = blockIdx.x * SCAN_BS + t;
  int v = (i < n) ? ideg[i] : 0;
  s[t] = v;
  __syncthreads();
  for (int d = 1; d < SCAN_BS; d <<= 1) {
    int u = (t >= d) ? s[t - d] : 0;
    __syncthreads();
    s[t] += u;
    __syncthreads();
  }
  if (i < n) {
    int excl = bbase[blockIdx.x] + s[t] - v;
    off[i] = excl;
    cur[i] = excl;
    dinv[i] = rsqrtf((float)v + 1.0f);
  }
}

__global__ __launch_bounds__(256) void k_fill(const int* __restrict__ src,
                                              const int* __restrict__ dst,
                                              int* __restrict__ cur,
                                              int* __restrict__ csr_src, int ne) {
  int stride = gridDim.x * blockDim.x;
  for (int e = blockIdx.x * blockDim.x + threadIdx.x; e < ne; e += stride) {
    int d = dst[e];
    int s = src[e];
    int p = atomicAdd(&cur[d], 1);
    csr_src[p] = s;
  }
}

// ---------------- W prep ----------------

__global__ __launch_bounds__(256) void k_wprep(const float* __restrict__ W0,
                                               const float* __restrict__ W1,
                                               const float* __restrict__ W2,
                                               u32* __restrict__ Wt) {
  const float* W = blockIdx.x == 0 ? W0 : (blockIdx.x == 1 ? W1 : W2);
  u32* o = Wt + (size_t)blockIdx.x * DIM * 64;
  int tid = threadIdx.x;
#pragma unroll
  for (int i = 0; i < 32; ++i) {
    int u = tid + i * 256;
    int c = u >> 6;
    int kk = u & 63;
    float lo = W[(size_t)(2 * kk) * DIM + c];
    float hi = W[(size_t)(2 * kk + 1) * DIM + c];
    o[u] = pk(lo, hi);
  }
}

// ---------------- MFMA GEMM ----------------
// Layer 0: Af != null  -> A = f32, no BN.
// Layers 1/2: Abf != null -> A = bf16 raw; BN scale/shift computed inline from
// stats (ssum/ssq/gamma/beta/invn), then relu, then bf16 for MFMA.

__global__ __launch_bounds__(256) void k_gemm(const float* __restrict__ Af,
                                              const u32* __restrict__ Abf,
                                              const u32* __restrict__ Wt,
                                              const float* __restrict__ dinv,
                                              const float* __restrict__ ssum,
                                              const float* __restrict__ ssq,
                                              const float* __restrict__ gamma,
                                              const float* __restrict__ beta,
                                              float invn,
                                              u32* __restrict__ C, int n) {
  __shared__ u32 sA[8192];
  __shared__ u32 sB[8192];
  __shared__ float sdv[DIM];
  __shared__ float ssc[DIM];
  __shared__ float ssh[DIM];
  int tid = threadIdx.x;
  int row0 = blockIdx.x * DIM;

  if (Abf && tid < DIM) {  // inline BN finalize (replaces k_bn)
    float mu = ssum[tid] * invn;
    float var = ssq[tid] * invn - mu * mu;
    float rstd = rsqrtf(var + BN_EPS);
    float s = rstd * gamma[tid];
    ssc[tid] = s;
    ssh[tid] = beta[tid] - mu * s;
  }
  {
    const uint4* w4 = (const uint4*)Wt;
#pragma unroll
    for (int i = 0; i < 8; ++i) {
      int u = tid + i * 256;
      int r = u >> 4, s = u & 15;
      uint4 v = w4[u];
      ((uint4*)sB)[r * 16 + (s ^ (r & 7))] = v;
    }
  }
  if (Abf) __syncthreads();  // ssc/ssh ready before A staging

#pragma unroll
  for (int i = 0; i < 8; ++i) {
    int u = tid + i * 256;
    int r = u >> 4, s = u & 15;
    int gr = row0 + r;
    uint4 pv = make_uint4(0u, 0u, 0u, 0u);
    if (gr < n) {
      if (Abf) {
        uint4 v = ((const uint4*)Abf)[(size_t)gr * 16 + s];
        int c = s * 8;
        float f0 = fmaxf(fmaf(bflo(v.x), ssc[c + 0], ssh[c + 0]), 0.f);
        float f1 = fmaxf(fmaf(bfhi(v.x), ssc[c + 1], ssh[c + 1]), 0.f);
        float f2 = fmaxf(fmaf(bflo(v.y), ssc[c + 2], ssh[c + 2]), 0.f);
        float f3 = fmaxf(fmaf(bfhi(v.y), ssc[c + 3], ssh[c + 3]), 0.f);
        float f4 = fmaxf(fmaf(bflo(v.z), ssc[c + 4], ssh[c + 4]), 0.f);
        float f5 = fmaxf(fmaf(bfhi(v.z), ssc[c + 5], ssh[c + 5]), 0.f);
        float f6 = fmaxf(fmaf(bflo(v.w), ssc[c + 6], ssh[c + 6]), 0.f);
        float f7 = fmaxf(fmaf(bfhi(v.w), ssc[c + 7], ssh[c + 7]), 0.f);
        pv.x = pk(f0, f1);
        pv.y = pk(f2, f3);
        pv.z = pk(f4, f5);
        pv.w = pk(f6, f7);
      } else {
        float4 v0 = ((const float4*)Af)[(size_t)gr * 32 + s * 2];
        float4 v1 = ((const float4*)Af)[(size_t)gr * 32 + s * 2 + 1];
        pv.x = pk(v0.x, v0.y);
        pv.y = pk(v0.z, v0.w);
        pv.z = pk(v1.x, v1.y);
        pv.w = pk(v1.z, v1.w);
      }
    }
    ((uint4*)sA)[r * 16 + (s ^ (r & 7))] = pv;
  }
  if (tid < DIM) sdv[tid] = (row0 + tid < n) ? dinv[row0 + tid] : 0.f;
  __syncthreads();

  int lane = tid & 63;
  int w = tid >> 6;
  int lr = lane & 15;
  int g = lane >> 4;
  f32x4 acc[2][8];
#pragma unroll
  for (int m = 0; m < 2; ++m)
#pragma unroll
    for (int nt = 0; nt < 8; ++nt) acc[m][nt] = (f32x4){0.f, 0.f, 0.f, 0.f};

#pragma unroll
  for (int kc = 0; kc < 4; ++kc) {
    short8 a[2], b[8];
#pragma unroll
    for (int m = 0; m < 2; ++m) {
      int r = w * 32 + m * 16 + lr;
      int sp = (kc * 4 + g) ^ (r & 7);
      a[m] = *(const short8*)&sA[(r * 16 + sp) * 4];
    }
#pragma unroll
    for (int nt = 0; nt < 8; ++nt) {
      int r = nt * 16 + lr;
      int sp = (kc * 4 + g) ^ (r & 7);
      b[nt] = *(const short8*)&sB[(r * 16 + sp) * 4];
    }
#pragma unroll
    for (int m = 0; m < 2; ++m)
#pragma unroll
      for (int nt = 0; nt < 8; ++nt)
        acc[m][nt] = __builtin_amdgcn_mfma_f32_16x16x32_bf16(a[m], b[nt], acc[m][nt], 0, 0, 0);
  }
  __syncthreads();

  {
    unsigned short* so = (unsigned short*)sA;
#pragma unroll
    for (int m = 0; m < 2; ++m) {
#pragma unroll
      for (int nt = 0; nt < 8; ++nt) {
#pragma unroll
        for (int r4 = 0; r4 < 4; ++r4) {
          int rl = w * 32 + m * 16 + g * 4 + r4;
          int col = ((nt ^ ((rl >> 2) & 7)) << 4) + lr;
          so[rl * DIM + col] = (unsigned short)bf16rne(acc[m][nt][r4] * sdv[rl]);
        }
      }
    }
  }
  __syncthreads();
#pragma unroll
  for (int i = 0; i < 8; ++i) {
    int u = tid + i * 256;
    int r = u >> 4, s = u & 15;
    if (row0 + r < n) {
      int sswz = (s & 1) | (((s >> 1) ^ ((r >> 2) & 7)) << 1);
      ((uint4*)C)[(size_t)(row0 + r) * 16 + s] = ((uint4*)sA)[r * 16 + sswz];
    }
  }
}

// ---------------- Aggregation: one node per 64-lane wave (proven R10/R11) ----
// Raw output stored bf16-packed (u32/lane). prev is bf16 raw of previous layer;
// its BN scale/shift computed inline from prev-layer stats.

__global__ __launch_bounds__(256) void k_agg(const u32* __restrict__ xw,
                                             const int* __restrict__ off,
                                             const int* __restrict__ csr_src,
                                             const float* __restrict__ dinv,
                                             const float* __restrict__ bias,
                                             const u32* __restrict__ prev,
                                             const float* __restrict__ psum,
                                             const float* __restrict__ psq,
                                             const float* __restrict__ pgam,
                                             const float* __restrict__ pbet,
                                             float invn,
                                             u32* __restrict__ out,
                                             float* __restrict__ ssum,
                                             float* __restrict__ ssq, int n) {
  int tid = threadIdx.x;
  int lane = tid & 63;
  int wave = tid >> 6;
  float2 bc = ((const float2*)bias)[lane];
  float2 ps, ph;
  if (prev) {  // inline BN finalize for residual path
    int c0 = lane * 2, c1 = c0 + 1;
    float m0 = psum[c0] * invn, m1 = psum[c1] * invn;
    float r0 = rsqrtf(psq[c0] * invn - m0 * m0 + BN_EPS);
    float r1 = rsqrtf(psq[c1] * invn - m1 * m1 + BN_EPS);
    ps.x = r0 * pgam[c0];
    ps.y = r1 * pgam[c1];
    ph.x = pbet[c0] - m0 * ps.x;
    ph.y = pbet[c1] - m1 * ps.y;
  }
  float s0 = 0.f, s1 = 0.f, q0 = 0.f, q1 = 0.f;
  int stride = gridDim.x * 4;

  for (int node = blockIdx.x * 4 + wave; node < n; node += stride) {
    int e0 = __builtin_amdgcn_readfirstlane(off[node]);
    int e1 = __builtin_amdgcn_readfirstlane(off[node + 1]);
    float a0, a1;
    {
      u32 s = xw[(size_t)node * 64 + lane];
      a0 = bflo(s);
      a1 = bfhi(s);
    }
    int e = e0;
    for (; e + 8 <= e1; e += 8) {
      int i0 = __builtin_amdgcn_readfirstlane(csr_src[e]);
      int i1 = __builtin_amdgcn_readfirstlane(csr_src[e + 1]);
      int i2 = __builtin_amdgcn_readfirstlane(csr_src[e + 2]);
      int i3 = __builtin_amdgcn_readfirstlane(csr_src[e + 3]);
      int i4 = __builtin_amdgcn_readfirstlane(csr_src[e + 4]);
      int i5 = __builtin_amdgcn_readfirstlane(csr_src[e + 5]);
      int i6 = __builtin_amdgcn_readfirstlane(csr_src[e + 6]);
      int i7 = __builtin_amdgcn_readfirstlane(csr_src[e + 7]);
      u32 v0 = xw[(size_t)i0 * 64 + lane];
      u32 v1 = xw[(size_t)i1 * 64 + lane];
      u32 v2 = xw[(size_t)i2 * 64 + lane];
      u32 v3 = xw[(size_t)i3 * 64 + lane];
      u32 v4 = xw[(size_t)i4 * 64 + lane];
      u32 v5 = xw[(size_t)i5 * 64 + lane];
      u32 v6 = xw[(size_t)i6 * 64 + lane];
      u32 v7 = xw[(size_t)i7 * 64 + lane];
      a0 += ((bflo(v0) + bflo(v1)) + (bflo(v2) + bflo(v3))) +
            ((bflo(v4) + bflo(v5)) + (bflo(v6) + bflo(v7)));
      a1 += ((bfhi(v0) + bfhi(v1)) + (bfhi(v2) + bfhi(v3))) +
            ((bfhi(v4) + bfhi(v5)) + (bfhi(v6) + bfhi(v7)));
    }
    for (; e + 4 <= e1; e += 4) {
      int i0 = __builtin_amdgcn_readfirstlane(csr_src[e]);
      int i1 = __builtin_amdgcn_readfirstlane(csr_src[e + 1]);
      int i2 = __builtin_amdgcn_readfirstlane(csr_src[e + 2]);
      int i3 = __builtin_amdgcn_readfirstlane(csr_src[e + 3]);
      u32 v0 = xw[(size_t)i0 * 64 + lane];
      u32 v1 = xw[(size_t)i1 * 64 + lane];
      u32 v2 = xw[(size_t)i2 * 64 + lane];
      u32 v3 = xw[(size_t)i3 * 64 + lane];
      a0 += (bflo(v0) + bflo(v1)) + (bflo(v2) + bflo(v3));
      a1 += (bfhi(v0) + bfhi(v1)) + (bfhi(v2) + bfhi(v3));
    }
    for (; e < e1; ++e) {
      int i0 = __builtin_amdgcn_readfirstlane(csr_src[e]);
      u32 v = xw[(size_t)i0 * 64 + lane];
      a0 += bflo(v);
      a1 += bfhi(v);
    }
    float di = dinv[node];
    float v0 = fmaf(di, a0, bc.x);
    float v1 = fmaf(di, a1, bc.y);
    if (prev) {
      u32 pv = prev[(size_t)node * 64 + lane];
      v0 += fmaxf(fmaf(bflo(pv), ps.x, ph.x), 0.f);
      v1 += fmaxf(fmaf(bfhi(pv), ps.y, ph.y), 0.f);
    }
    out[(size_t)node * 64 + lane] = pk(v0, v1);
    s0 += v0;
    s1 += v1;
    q0 = fmaf(v0, v0, q0);
    q1 = fmaf(v1, v1, q1);
  }

  __shared__ float red[4][64][2];
  red[wave][lane][0] = s0;
  red[wave][lane][1] = s1;
  __syncthreads();
  if (wave == 0) {
    float t0 = (red[0][lane][0] + red[1][lane][0]) + (red[2][lane][0] + red[3][lane][0]);
    float t1 = (red[0][lane][1] + red[1][lane][1]) + (red[2][lane][1] + red[3][lane][1]);
    atomicAdd(&ssum[lane * 2], t0);
    atomicAdd(&ssum[lane * 2 + 1], t1);
  }
  __syncthreads();
  red[wave][lane][0] = q0;
  red[wave][lane][1] = q1;
  __syncthreads();
  if (wave == 0) {
    float t0 = (red[0][lane][0] + red[1][lane][0]) + (red[2][lane][0] + red[3][lane][0]);
    float t1 = (red[0][lane][1] + red[1][lane][1]) + (red[2][lane][1] + red[3][lane][1]);
    atomicAdd(&ssq[lane * 2], t0);
    atomicAdd(&ssq[lane * 2 + 1], t1);
  }
}

// ---------------- final normalize/relu (BN finalize inline) ----------------

__global__ __launch_bounds__(256) void k_norm(const u32* __restrict__ in,
                                              float* __restrict__ out,
                                              const float* __restrict__ ssum,
                                              const float* __restrict__ ssq,
                                              const float* __restrict__ gamma,
                                              const float* __restrict__ beta,
                                              float invn, int n32) {
  int stride = gridDim.x * blockDim.x;
  for (int j = blockIdx.x * blockDim.x + threadIdx.x; j < n32; j += stride) {
    int cg = j & 31;  // 4 cols per uint2
    float4 sm = ((const float4*)ssum)[cg];
    float4 sq = ((const float4*)ssq)[cg];
    float4 g = ((const float4*)gamma)[cg];
    float4 b = ((const float4*)beta)[cg];
    float4 mu = make_float4(sm.x * invn, sm.y * invn, sm.z * invn, sm.w * invn);
    float4 sc, sh;
    sc.x = rsqrtf(sq.x * invn - mu.x * mu.x + BN_EPS) * g.x;
    sc.y = rsqrtf(sq.y * invn - mu.y * mu.y + BN_EPS) * g.y;
    sc.z = rsqrtf(sq.z * invn - mu.z * mu.z + BN_EPS) * g.z;
    sc.w = rsqrtf(sq.w * invn - mu.w * mu.w + BN_EPS) * g.w;
    sh.x = b.x - mu.x * sc.x;
    sh.y = b.y - mu.y * sc.y;
    sh.z = b.z - mu.z * sc.z;
    sh.w = b.w - mu.w * sc.w;
    uint2 v = ((const uint2*)in)[j];
    float4 o;
    o.x = fmaxf(fmaf(bflo(v.x), sc.x, sh.x), 0.f);
    o.y = fmaxf(fmaf(bfhi(v.x), sc.y, sh.y), 0.f);
    o.z = fmaxf(fmaf(bflo(v.y), sc.z, sh.z), 0.f);
    o.w = fmaxf(fmaf(bfhi(v.y), sc.w, sh.w), 0.f);
    ((float4*)out)[j] = o;
  }
}

// ---------------- launch ----------------

extern "C" void kernel_launch(void* const* d_in, const int* in_sizes, int n_in,
                              void* d_out, int out_size, void* d_ws, size_t ws_size,
                              hipStream_t stream) {
  const float* x = (const float*)d_in[0];
  const int* ei = (const int*)d_in[1];
  int n = in_sizes[0] / DIM;   // 100000
  int ne = in_sizes[1] / 2;    // 1600000
  const int* src = ei;
  const int* dst = ei + ne;

  const float *W[3], *B[3], *G[3], *Bt[3];
  if (n_in >= 14) {
    for (int l = 0; l < 3; ++l) {
      W[l] = (const float*)d_in[2 + l];
      B[l] = (const float*)d_in[5 + l];
      G[l] = (const float*)d_in[8 + l];
      Bt[l] = (const float*)d_in[11 + l];
    }
  } else {
    for (int l = 0; l < 3; ++l) {
      W[l] = (const float*)d_in[2] + (size_t)l * DIM * DIM;
      B[l] = (const float*)d_in[3] + (size_t)l * DIM;
      G[l] = (const float*)d_in[4] + (size_t)l * DIM;
      Bt[l] = (const float*)d_in[5] + (size_t)l * DIM;
    }
  }

  float* out = (float*)d_out;

  char* p = (char*)d_ws;
  auto carve = [&](size_t bytes) {
    void* q = (void*)p;
    p += (bytes + 255) & ~(size_t)255;
    return q;
  };
  int* ideg = (int*)carve((size_t)n * 4);
  int* coff = (int*)carve((size_t)(n + 1) * 4);
  int* cur = (int*)carve((size_t)n * 4);
  float* dinv = (float*)carve((size_t)n * 4);
  int* csr_src = (int*)carve((size_t)ne * 4);
  u32* xw = (u32*)carve((size_t)n * DIM * 2);    // bf16 packed
  u32* rawA = (u32*)carve((size_t)n * DIM * 2);  // bf16 raw layer outs
  u32* rawB = (u32*)carve((size_t)n * DIM * 2);
  u32* wt = (u32*)carve(3 * DIM * 64 * 4);
  float* stats = (float*)carve(3 * 256 * 4);
  int* bsum = (int*)carve(256 * 4);
  int* bbase = (int*)carve(256 * 4);

  hipMemsetAsync(ideg, 0, (size_t)n * 4, stream);
  hipMemsetAsync(stats, 0, 3 * 256 * 4, stream);

  int nscan = (n + SCAN_BS - 1) / SCAN_BS;

  k_wprep<<<3, 256, 0, stream>>>(W[0], W[1], W[2], wt);
  k_count<<<1024, 256, 0, stream>>>(dst, ideg, ne);
  k_scan1<<<nscan, SCAN_BS, 0, stream>>>(ideg, bsum, n);
  k_scan2<<<1, 256, 0, stream>>>(bsum, bbase, nscan, coff, n, ne);
  k_scan3<<<nscan, SCAN_BS, 0, stream>>>(ideg, bbase, coff, cur, dinv, n);
  k_fill<<<1024, 256, 0, stream>>>(src, dst, cur, csr_src, ne);

  float invn = 1.0f / (float)n;
  int nblk = (n + DIM - 1) / DIM;
  const int AGG_GRID = 2048;   // proven best (R6/R7); 4096 regressed (R9)

  float* ss0 = stats;
  float* ss1 = stats + 256;
  float* ss2 = stats + 512;

  // layer 0: gemm(x f32) -> xw ; agg -> rawA bf16 ; stats -> ss0
  k_gemm<<<nblk, 256, 0, stream>>>(x, nullptr, wt, dinv,
                                   nullptr, nullptr, nullptr, nullptr, 0.f, xw, n);
  k_agg<<<AGG_GRID, 256, 0, stream>>>(xw, coff, csr_src, dinv, B[0], nullptr,
                                      nullptr, nullptr, nullptr, nullptr, invn,
                                      rawA, ss0, ss0 + 128, n);

  // layer 1: gemm(bn0(rawA)) -> xw ; agg(prev=bn0(rawA)) -> rawB ; stats -> ss1
  k_gemm<<<nblk, 256, 0, stream>>>(nullptr, rawA, wt + (size_t)DIM * 64, dinv,
                                   ss0, ss0 + 128, G[0], Bt[0], invn, xw, n);
  k_agg<<<AGG_GRID, 256, 0, stream>>>(xw, coff, csr_src, dinv, B[1], rawA,
                                      ss0, ss0 + 128, G[0], Bt[0], invn,
                                      rawB, ss1, ss1 + 128, n);

  // layer 2: gemm(bn1(rawB)) -> xw ; agg(prev=bn1(rawB)) -> rawA ; stats -> ss2
  k_gemm<<<nblk, 256, 0, stream>>>(nullptr, rawB, wt + (size_t)2 * DIM * 64, dinv,
                                   ss1, ss1 + 128, G[1], Bt[1], invn, xw, n);
  k_agg<<<AGG_GRID, 256, 0, stream>>>(xw, coff, csr_src, dinv, B[2], rawB,
                                      ss1, ss1 + 128, G[1], Bt[1], invn,
                                      rawA, ss2, ss2 + 128, n);

  // final normalize into d_out
  k_norm<<<2048, 256, 0, stream>>>(rawA, out, ss2, ss2 + 128, G[2], Bt[2], invn, n * 32);
}

// Round 13
// 758.213 us; speedup vs baseline: 2.4221x; 1.0008x over previous
//
#include <hip/hip_runtime.h>

#define DIM 128
#define BN_EPS 1e-5f
#define SCAN_BS 512
typedef unsigned int u32;
typedef __attribute__((ext_vector_type(8))) short short8;
typedef __attribute__((ext_vector_type(4))) float f32x4;

__device__ __forceinline__ u32 bf16rne(float x) {
  u32 u = __float_as_uint(x);
  return (u + 0x7FFFu + ((u >> 16) & 1u)) >> 16;
}
__device__ __forceinline__ float bflo(u32 u) { return __uint_as_float(u << 16); }
__device__ __forceinline__ float bfhi(u32 u) { return __uint_as_float(u & 0xFFFF0000u); }
__device__ __forceinline__ u32 pk(float a, float b) { return bf16rne(a) | (bf16rne(b) << 16); }
#define RF __builtin_amdgcn_readfirstlane

// ---------------- CSR build ----------------

__global__ __launch_bounds__(256) void k_count(const int* __restrict__ dst,
                                               int* __restrict__ ideg, int ne) {
  int stride = gridDim.x * blockDim.x;
  for (int e = blockIdx.x * blockDim.x + threadIdx.x; e < ne; e += stride)
    atomicAdd(&ideg[dst[e]], 1);
}

__global__ __launch_bounds__(SCAN_BS) void k_scan1(const int* __restrict__ ideg,
                                                   int* __restrict__ bsum, int n) {
  __shared__ int red[SCAN_BS];
  int t = threadIdx.x;
  int i = blockIdx.x * SCAN_BS + t;
  red[t] = (i < n) ? ideg[i] : 0;
  __syncthreads();
  for (int d = SCAN_BS / 2; d > 0; d >>= 1) {
    if (t < d) red[t] += red[t + d];
    __syncthreads();
  }
  if (t == 0) bsum[blockIdx.x] = red[0];
}

__global__ __launch_bounds__(256) void k_scan2(const int* __restrict__ bsum,
                                               int* __restrict__ bbase, int nb,
                                               int* __restrict__ off, int n, int ne) {
  __shared__ int s[256];
  int t = threadIdx.x;
  s[t] = (t < nb) ? bsum[t] : 0;
  __syncthreads();
  for (int d = 1; d < 256; d <<= 1) {
    int v = (t >= d) ? s[t - d] : 0;
    __syncthreads();
    s[t] += v;
    __syncthreads();
  }
  if (t < nb) bbase[t] = (t == 0) ? 0 : s[t - 1];
  if (t == 0) off[n] = ne;
}

__global__ __launch_bounds__(SCAN_BS) void k_scan3(const int* __restrict__ ideg,
                                                   const int* __restrict__ bbase,
                                                   int* __restrict__ off,
                                                   int* __restrict__ cur,
                                                   float* __restrict__ dinv, int n) {
  __shared__ int s[SCAN_BS];
  int t = threadIdx.x;
  int i = blockIdx.x * SCAN_BS + t;
  int v = (i < n) ? ideg[i] : 0;
  s[t] = v;
  __syncthreads();
  for (int d = 1; d < SCAN_BS; d <<= 1) {
    int u = (t >= d) ? s[t - d] : 0;
    __syncthreads();
    s[t] += u;
    __syncthreads();
  }
  if (i < n) {
    int excl = bbase[blockIdx.x] + s[t] - v;
    off[i] = excl;
    cur[i] = excl;
    dinv[i] = rsqrtf((float)v + 1.0f);
  }
}

__global__ __launch_bounds__(256) void k_fill(const int* __restrict__ src,
                                              const int* __restrict__ dst,
                                              int* __restrict__ cur,
                                              int* __restrict__ csr_src, int ne) {
  int stride = gridDim.x * blockDim.x;
  for (int e = blockIdx.x * blockDim.x + threadIdx.x; e < ne; e += stride) {
    int d = dst[e];
    int s = src[e];
    int p = atomicAdd(&cur[d], 1);
    csr_src[p] = s;
  }
}

// ---------------- W prep ----------------

__global__ __launch_bounds__(256) void k_wprep(const float* __restrict__ W0,
                                               const float* __restrict__ W1,
                                               const float* __restrict__ W2,
                                               u32* __restrict__ Wt) {
  const float* W = blockIdx.x == 0 ? W0 : (blockIdx.x == 1 ? W1 : W2);
  u32* o = Wt + (size_t)blockIdx.x * DIM * 64;
  int tid = threadIdx.x;
#pragma unroll
  for (int i = 0; i < 32; ++i) {
    int u = tid + i * 256;
    int c = u >> 6;
    int kk = u & 63;
    float lo = W[(size_t)(2 * kk) * DIM + c];
    float hi = W[(size_t)(2 * kk + 1) * DIM + c];
    o[u] = pk(lo, hi);
  }
}

// ---------------- MFMA GEMM (unchanged from R12) ----------------

__global__ __launch_bounds__(256) void k_gemm(const float* __restrict__ Af,
                                              const u32* __restrict__ Abf,
                                              const u32* __restrict__ Wt,
                                              const float* __restrict__ dinv,
                                              const float* __restrict__ ssum,
                                              const float* __restrict__ ssq,
                                              const float* __restrict__ gamma,
                                              const float* __restrict__ beta,
                                              float invn,
                                              u32* __restrict__ C, int n) {
  __shared__ u32 sA[8192];
  __shared__ u32 sB[8192];
  __shared__ float sdv[DIM];
  __shared__ float ssc[DIM];
  __shared__ float ssh[DIM];
  int tid = threadIdx.x;
  int row0 = blockIdx.x * DIM;

  if (Abf && tid < DIM) {
    float mu = ssum[tid] * invn;
    float var = ssq[tid] * invn - mu * mu;
    float rstd = rsqrtf(var + BN_EPS);
    float s = rstd * gamma[tid];
    ssc[tid] = s;
    ssh[tid] = beta[tid] - mu * s;
  }
  {
    const uint4* w4 = (const uint4*)Wt;
#pragma unroll
    for (int i = 0; i < 8; ++i) {
      int u = tid + i * 256;
      int r = u >> 4, s = u & 15;
      uint4 v = w4[u];
      ((uint4*)sB)[r * 16 + (s ^ (r & 7))] = v;
    }
  }
  if (Abf) __syncthreads();

#pragma unroll
  for (int i = 0; i < 8; ++i) {
    int u = tid + i * 256;
    int r = u >> 4, s = u & 15;
    int gr = row0 + r;
    uint4 pv = make_uint4(0u, 0u, 0u, 0u);
    if (gr < n) {
      if (Abf) {
        uint4 v = ((const uint4*)Abf)[(size_t)gr * 16 + s];
        int c = s * 8;
        float f0 = fmaxf(fmaf(bflo(v.x), ssc[c + 0], ssh[c + 0]), 0.f);
        float f1 = fmaxf(fmaf(bfhi(v.x), ssc[c + 1], ssh[c + 1]), 0.f);
        float f2 = fmaxf(fmaf(bflo(v.y), ssc[c + 2], ssh[c + 2]), 0.f);
        float f3 = fmaxf(fmaf(bfhi(v.y), ssc[c + 3], ssh[c + 3]), 0.f);
        float f4 = fmaxf(fmaf(bflo(v.z), ssc[c + 4], ssh[c + 4]), 0.f);
        float f5 = fmaxf(fmaf(bfhi(v.z), ssc[c + 5], ssh[c + 5]), 0.f);
        float f6 = fmaxf(fmaf(bflo(v.w), ssc[c + 6], ssh[c + 6]), 0.f);
        float f7 = fmaxf(fmaf(bfhi(v.w), ssc[c + 7], ssh[c + 7]), 0.f);
        pv.x = pk(f0, f1);
        pv.y = pk(f2, f3);
        pv.z = pk(f4, f5);
        pv.w = pk(f6, f7);
      } else {
        float4 v0 = ((const float4*)Af)[(size_t)gr * 32 + s * 2];
        float4 v1 = ((const float4*)Af)[(size_t)gr * 32 + s * 2 + 1];
        pv.x = pk(v0.x, v0.y);
        pv.y = pk(v0.z, v0.w);
        pv.z = pk(v1.x, v1.y);
        pv.w = pk(v1.z, v1.w);
      }
    }
    ((uint4*)sA)[r * 16 + (s ^ (r & 7))] = pv;
  }
  if (tid < DIM) sdv[tid] = (row0 + tid < n) ? dinv[row0 + tid] : 0.f;
  __syncthreads();

  int lane = tid & 63;
  int w = tid >> 6;
  int lr = lane & 15;
  int g = lane >> 4;
  f32x4 acc[2][8];
#pragma unroll
  for (int m = 0; m < 2; ++m)
#pragma unroll
    for (int nt = 0; nt < 8; ++nt) acc[m][nt] = (f32x4){0.f, 0.f, 0.f, 0.f};

#pragma unroll
  for (int kc = 0; kc < 4; ++kc) {
    short8 a[2], b[8];
#pragma unroll
    for (int m = 0; m < 2; ++m) {
      int r = w * 32 + m * 16 + lr;
      int sp = (kc * 4 + g) ^ (r & 7);
      a[m] = *(const short8*)&sA[(r * 16 + sp) * 4];
    }
#pragma unroll
    for (int nt = 0; nt < 8; ++nt) {
      int r = nt * 16 + lr;
      int sp = (kc * 4 + g) ^ (r & 7);
      b[nt] = *(const short8*)&sB[(r * 16 + sp) * 4];
    }
#pragma unroll
    for (int m = 0; m < 2; ++m)
#pragma unroll
      for (int nt = 0; nt < 8; ++nt)
        acc[m][nt] = __builtin_amdgcn_mfma_f32_16x16x32_bf16(a[m], b[nt], acc[m][nt], 0, 0, 0);
  }
  __syncthreads();

  {
    unsigned short* so = (unsigned short*)sA;
#pragma unroll
    for (int m = 0; m < 2; ++m) {
#pragma unroll
      for (int nt = 0; nt < 8; ++nt) {
#pragma unroll
        for (int r4 = 0; r4 < 4; ++r4) {
          int rl = w * 32 + m * 16 + g * 4 + r4;
          int col = ((nt ^ ((rl >> 2) & 7)) << 4) + lr;
          so[rl * DIM + col] = (unsigned short)bf16rne(acc[m][nt][r4] * sdv[rl]);
        }
      }
    }
  }
  __syncthreads();
#pragma unroll
  for (int i = 0; i < 8; ++i) {
    int u = tid + i * 256;
    int r = u >> 4, s = u & 15;
    if (row0 + r < n) {
      int sswz = (s & 1) | (((s >> 1) ^ ((r >> 2) & 7)) << 1);
      ((uint4*)C)[(size_t)(row0 + r) * 16 + s] = ((uint4*)sA)[r * 16 + sswz];
    }
  }
}

// ---------------- Aggregation: TWO nodes per wave, interleaved gather streams ----
// Stream B's index loads overlap stream A's row gathers -> ~2x outstanding VMEM.

__global__ __launch_bounds__(256) void k_agg(const u32* __restrict__ xw,
                                             const int* __restrict__ off,
                                             const int* __restrict__ csr_src,
                                             const float* __restrict__ dinv,
                                             const float* __restrict__ bias,
                                             const u32* __restrict__ prev,
                                             const float* __restrict__ psum,
                                             const float* __restrict__ psq,
                                             const float* __restrict__ pgam,
                                             const float* __restrict__ pbet,
                                             float invn,
                                             u32* __restrict__ out,
                                             float* __restrict__ ssum,
                                             float* __restrict__ ssq, int n) {
  int tid = threadIdx.x;
  int lane = tid & 63;
  int wave = tid >> 6;
  float2 bc = ((const float2*)bias)[lane];
  float2 ps, ph;
  if (prev) {
    int c0 = lane * 2, c1 = c0 + 1;
    float m0 = psum[c0] * invn, m1 = psum[c1] * invn;
    float r0 = rsqrtf(psq[c0] * invn - m0 * m0 + BN_EPS);
    float r1 = rsqrtf(psq[c1] * invn - m1 * m1 + BN_EPS);
    ps.x = r0 * pgam[c0];
    ps.y = r1 * pgam[c1];
    ph.x = pbet[c0] - m0 * ps.x;
    ph.y = pbet[c1] - m1 * ps.y;
  }
  float s0 = 0.f, s1 = 0.f, q0 = 0.f, q1 = 0.f;
  int stride = gridDim.x * 8;

  for (int na = blockIdx.x * 8 + wave * 2; na < n; na += stride) {
    int nb = na + 1;
    bool hb = nb < n;
    int a0 = RF(off[na]);
    int a1 = RF(off[na + 1]);
    int b0 = 0, b1 = 0;
    if (hb) {
      b0 = RF(off[nb]);
      b1 = RF(off[nb + 1]);
    }
    float aA0, aA1, aB0 = 0.f, aB1 = 0.f;
    {
      u32 s = xw[(size_t)na * 64 + lane];
      aA0 = bflo(s);
      aA1 = bfhi(s);
    }
    if (hb) {
      u32 s = xw[(size_t)nb * 64 + lane];
      aB0 = bflo(s);
      aB1 = bfhi(s);
    }
    int ea = a0, eb = b0;
    // interleaved main loop: 4 edges from each stream
    while (ea + 4 <= a1 && eb + 4 <= b1) {
      int iA0 = RF(csr_src[ea]);
      int iA1 = RF(csr_src[ea + 1]);
      int iA2 = RF(csr_src[ea + 2]);
      int iA3 = RF(csr_src[ea + 3]);
      int iB0 = RF(csr_src[eb]);
      int iB1 = RF(csr_src[eb + 1]);
      int iB2 = RF(csr_src[eb + 2]);
      int iB3 = RF(csr_src[eb + 3]);
      u32 vA0 = xw[(size_t)iA0 * 64 + lane];
      u32 vA1 = xw[(size_t)iA1 * 64 + lane];
      u32 vA2 = xw[(size_t)iA2 * 64 + lane];
      u32 vA3 = xw[(size_t)iA3 * 64 + lane];
      u32 vB0 = xw[(size_t)iB0 * 64 + lane];
      u32 vB1 = xw[(size_t)iB1 * 64 + lane];
      u32 vB2 = xw[(size_t)iB2 * 64 + lane];
      u32 vB3 = xw[(size_t)iB3 * 64 + lane];
      aA0 += (bflo(vA0) + bflo(vA1)) + (bflo(vA2) + bflo(vA3));
      aA1 += (bfhi(vA0) + bfhi(vA1)) + (bfhi(vA2) + bfhi(vA3));
      aB0 += (bflo(vB0) + bflo(vB1)) + (bflo(vB2) + bflo(vB3));
      aB1 += (bfhi(vB0) + bfhi(vB1)) + (bfhi(vB2) + bfhi(vB3));
      ea += 4;
      eb += 4;
    }
    // drain A
    for (; ea + 8 <= a1; ea += 8) {
      int i0 = RF(csr_src[ea]);
      int i1 = RF(csr_src[ea + 1]);
      int i2 = RF(csr_src[ea + 2]);
      int i3 = RF(csr_src[ea + 3]);
      int i4 = RF(csr_src[ea + 4]);
      int i5 = RF(csr_src[ea + 5]);
      int i6 = RF(csr_src[ea + 6]);
      int i7 = RF(csr_src[ea + 7]);
      u32 v0 = xw[(size_t)i0 * 64 + lane];
      u32 v1 = xw[(size_t)i1 * 64 + lane];
      u32 v2 = xw[(size_t)i2 * 64 + lane];
      u32 v3 = xw[(size_t)i3 * 64 + lane];
      u32 v4 = xw[(size_t)i4 * 64 + lane];
      u32 v5 = xw[(size_t)i5 * 64 + lane];
      u32 v6 = xw[(size_t)i6 * 64 + lane];
      u32 v7 = xw[(size_t)i7 * 64 + lane];
      aA0 += ((bflo(v0) + bflo(v1)) + (bflo(v2) + bflo(v3))) +
             ((bflo(v4) + bflo(v5)) + (bflo(v6) + bflo(v7)));
      aA1 += ((bfhi(v0) + bfhi(v1)) + (bfhi(v2) + bfhi(v3))) +
             ((bfhi(v4) + bfhi(v5)) + (bfhi(v6) + bfhi(v7)));
    }
    for (; ea + 4 <= a1; ea += 4) {
      int i0 = RF(csr_src[ea]);
      int i1 = RF(csr_src[ea + 1]);
      int i2 = RF(csr_src[ea + 2]);
      int i3 = RF(csr_src[ea + 3]);
      u32 v0 = xw[(size_t)i0 * 64 + lane];
      u32 v1 = xw[(size_t)i1 * 64 + lane];
      u32 v2 = xw[(size_t)i2 * 64 + lane];
      u32 v3 = xw[(size_t)i3 * 64 + lane];
      aA0 += (bflo(v0) + bflo(v1)) + (bflo(v2) + bflo(v3));
      aA1 += (bfhi(v0) + bfhi(v1)) + (bfhi(v2) + bfhi(v3));
    }
    for (; ea < a1; ++ea) {
      int i0 = RF(csr_src[ea]);
      u32 v = xw[(size_t)i0 * 64 + lane];
      aA0 += bflo(v);
      aA1 += bfhi(v);
    }
    // drain B (no-op when !hb since b0==b1==0)
    for (; eb + 8 <= b1; eb += 8) {
      int i0 = RF(csr_src[eb]);
      int i1 = RF(csr_src[eb + 1]);
      int i2 = RF(csr_src[eb + 2]);
      int i3 = RF(csr_src[eb + 3]);
      int i4 = RF(csr_src[eb + 4]);
      int i5 = RF(csr_src[eb + 5]);
      int i6 = RF(csr_src[eb + 6]);
      int i7 = RF(csr_src[eb + 7]);
      u32 v0 = xw[(size_t)i0 * 64 + lane];
      u32 v1 = xw[(size_t)i1 * 64 + lane];
      u32 v2 = xw[(size_t)i2 * 64 + lane];
      u32 v3 = xw[(size_t)i3 * 64 + lane];
      u32 v4 = xw[(size_t)i4 * 64 + lane];
      u32 v5 = xw[(size_t)i5 * 64 + lane];
      u32 v6 = xw[(size_t)i6 * 64 + lane];
      u32 v7 = xw[(size_t)i7 * 64 + lane];
      aB0 += ((bflo(v0) + bflo(v1)) + (bflo(v2) + bflo(v3))) +
             ((bflo(v4) + bflo(v5)) + (bflo(v6) + bflo(v7)));
      aB1 += ((bfhi(v0) + bfhi(v1)) + (bfhi(v2) + bfhi(v3))) +
             ((bfhi(v4) + bfhi(v5)) + (bfhi(v6) + bfhi(v7)));
    }
    for (; eb + 4 <= b1; eb += 4) {
      int i0 = RF(csr_src[eb]);
      int i1 = RF(csr_src[eb + 1]);
      int i2 = RF(csr_src[eb + 2]);
      int i3 = RF(csr_src[eb + 3]);
      u32 v0 = xw[(size_t)i0 * 64 + lane];
      u32 v1 = xw[(size_t)i1 * 64 + lane];
      u32 v2 = xw[(size_t)i2 * 64 + lane];
      u32 v3 = xw[(size_t)i3 * 64 + lane];
      aB0 += (bflo(v0) + bflo(v1)) + (bflo(v2) + bflo(v3));
      aB1 += (bfhi(v0) + bfhi(v1)) + (bfhi(v2) + bfhi(v3));
    }
    for (; eb < b1; ++eb) {
      int i0 = RF(csr_src[eb]);
      u32 v = xw[(size_t)i0 * 64 + lane];
      aB0 += bflo(v);
      aB1 += bfhi(v);
    }
    // finalize A
    {
      float di = dinv[na];
      float v0 = fmaf(di, aA0, bc.x);
      float v1 = fmaf(di, aA1, bc.y);
      if (prev) {
        u32 pv = prev[(size_t)na * 64 + lane];
        v0 += fmaxf(fmaf(bflo(pv), ps.x, ph.x), 0.f);
        v1 += fmaxf(fmaf(bfhi(pv), ps.y, ph.y), 0.f);
      }
      out[(size_t)na * 64 + lane] = pk(v0, v1);
      s0 += v0;
      s1 += v1;
      q0 = fmaf(v0, v0, q0);
      q1 = fmaf(v1, v1, q1);
    }
    // finalize B
    if (hb) {
      float di = dinv[nb];
      float v0 = fmaf(di, aB0, bc.x);
      float v1 = fmaf(di, aB1, bc.y);
      if (prev) {
        u32 pv = prev[(size_t)nb * 64 + lane];
        v0 += fmaxf(fmaf(bflo(pv), ps.x, ph.x), 0.f);
        v1 += fmaxf(fmaf(bfhi(pv), ps.y, ph.y), 0.f);
      }
      out[(size_t)nb * 64 + lane] = pk(v0, v1);
      s0 += v0;
      s1 += v1;
      q0 = fmaf(v0, v0, q0);
      q1 = fmaf(v1, v1, q1);
    }
  }

  __shared__ float red[4][64][2];
  red[wave][lane][0] = s0;
  red[wave][lane][1] = s1;
  __syncthreads();
  if (wave == 0) {
    float t0 = (red[0][lane][0] + red[1][lane][0]) + (red[2][lane][0] + red[3][lane][0]);
    float t1 = (red[0][lane][1] + red[1][lane][1]) + (red[2][lane][1] + red[3][lane][1]);
    atomicAdd(&ssum[lane * 2], t0);
    atomicAdd(&ssum[lane * 2 + 1], t1);
  }
  __syncthreads();
  red[wave][lane][0] = q0;
  red[wave][lane][1] = q1;
  __syncthreads();
  if (wave == 0) {
    float t0 = (red[0][lane][0] + red[1][lane][0]) + (red[2][lane][0] + red[3][lane][0]);
    float t1 = (red[0][lane][1] + red[1][lane][1]) + (red[2][lane][1] + red[3][lane][1]);
    atomicAdd(&ssq[lane * 2], t0);
    atomicAdd(&ssq[lane * 2 + 1], t1);
  }
}

// ---------------- final normalize/relu (BN finalize inline) ----------------

__global__ __launch_bounds__(256) void k_norm(const u32* __restrict__ in,
                                              float* __restrict__ out,
                                              const float* __restrict__ ssum,
                                              const float* __restrict__ ssq,
                                              const float* __restrict__ gamma,
                                              const float* __restrict__ beta,
                                              float invn, int n32) {
  int stride = gridDim.x * blockDim.x;
  for (int j = blockIdx.x * blockDim.x + threadIdx.x; j < n32; j += stride) {
    int cg = j & 31;
    float4 sm = ((const float4*)ssum)[cg];
    float4 sq = ((const float4*)ssq)[cg];
    float4 g = ((const float4*)gamma)[cg];
    float4 b = ((const float4*)beta)[cg];
    float4 mu = make_float4(sm.x * invn, sm.y * invn, sm.z * invn, sm.w * invn);
    float4 sc, sh;
    sc.x = rsqrtf(sq.x * invn - mu.x * mu.x + BN_EPS) * g.x;
    sc.y = rsqrtf(sq.y * invn - mu.y * mu.y + BN_EPS) * g.y;
    sc.z = rsqrtf(sq.z * invn - mu.z * mu.z + BN_EPS) * g.z;
    sc.w = rsqrtf(sq.w * invn - mu.w * mu.w + BN_EPS) * g.w;
    sh.x = b.x - mu.x * sc.x;
    sh.y = b.y - mu.y * sc.y;
    sh.z = b.z - mu.z * sc.z;
    sh.w = b.w - mu.w * sc.w;
    uint2 v = ((const uint2*)in)[j];
    float4 o;
    o.x = fmaxf(fmaf(bflo(v.x), sc.x, sh.x), 0.f);
    o.y = fmaxf(fmaf(bfhi(v.x), sc.y, sh.y), 0.f);
    o.z = fmaxf(fmaf(bflo(v.y), sc.z, sh.z), 0.f);
    o.w = fmaxf(fmaf(bfhi(v.y), sc.w, sh.w), 0.f);
    ((float4*)out)[j] = o;
  }
}

// ---------------- launch ----------------

extern "C" void kernel_launch(void* const* d_in, const int* in_sizes, int n_in,
                              void* d_out, int out_size, void* d_ws, size_t ws_size,
                              hipStream_t stream) {
  const float* x = (const float*)d_in[0];
  const int* ei = (const int*)d_in[1];
  int n = in_sizes[0] / DIM;   // 100000
  int ne = in_sizes[1] / 2;    // 1600000
  const int* src = ei;
  const int* dst = ei + ne;

  const float *W[3], *B[3], *G[3], *Bt[3];
  if (n_in >= 14) {
    for (int l = 0; l < 3; ++l) {
      W[l] = (const float*)d_in[2 + l];
      B[l] = (const float*)d_in[5 + l];
      G[l] = (const float*)d_in[8 + l];
      Bt[l] = (const float*)d_in[11 + l];
    }
  } else {
    for (int l = 0; l < 3; ++l) {
      W[l] = (const float*)d_in[2] + (size_t)l * DIM * DIM;
      B[l] = (const float*)d_in[3] + (size_t)l * DIM;
      G[l] = (const float*)d_in[4] + (size_t)l * DIM;
      Bt[l] = (const float*)d_in[5] + (size_t)l * DIM;
    }
  }

  float* out = (float*)d_out;

  char* p = (char*)d_ws;
  auto carve = [&](size_t bytes) {
    void* q = (void*)p;
    p += (bytes + 255) & ~(size_t)255;
    return q;
  };
  int* ideg = (int*)carve((size_t)n * 4);
  int* coff = (int*)carve((size_t)(n + 1) * 4);
  int* cur = (int*)carve((size_t)n * 4);
  float* dinv = (float*)carve((size_t)n * 4);
  int* csr_src = (int*)carve((size_t)ne * 4);
  u32* xw = (u32*)carve((size_t)n * DIM * 2);
  u32* rawA = (u32*)carve((size_t)n * DIM * 2);
  u32* rawB = (u32*)carve((size_t)n * DIM * 2);
  u32* wt = (u32*)carve(3 * DIM * 64 * 4);
  float* stats = (float*)carve(3 * 256 * 4);
  int* bsum = (int*)carve(256 * 4);
  int* bbase = (int*)carve(256 * 4);

  hipMemsetAsync(ideg, 0, (size_t)n * 4, stream);
  hipMemsetAsync(stats, 0, 3 * 256 * 4, stream);

  int nscan = (n + SCAN_BS - 1) / SCAN_BS;

  k_wprep<<<3, 256, 0, stream>>>(W[0], W[1], W[2], wt);
  k_count<<<1024, 256, 0, stream>>>(dst, ideg, ne);
  k_scan1<<<nscan, SCAN_BS, 0, stream>>>(ideg, bsum, n);
  k_scan2<<<1, 256, 0, stream>>>(bsum, bbase, nscan, coff, n, ne);
  k_scan3<<<nscan, SCAN_BS, 0, stream>>>(ideg, bbase, coff, cur, dinv, n);
  k_fill<<<1024, 256, 0, stream>>>(src, dst, cur, csr_src, ne);

  float invn = 1.0f / (float)n;
  int nblk = (n + DIM - 1) / DIM;
  const int AGG_GRID = 2048;   // proven best (R6/R7); 4096 regressed (R9)

  float* ss0 = stats;
  float* ss1 = stats + 256;
  float* ss2 = stats + 512;

  // layer 0
  k_gemm<<<nblk, 256, 0, stream>>>(x, nullptr, wt, dinv,
                                   nullptr, nullptr, nullptr, nullptr, 0.f, xw, n);
  k_agg<<<AGG_GRID, 256, 0, stream>>>(xw, coff, csr_src, dinv, B[0], nullptr,
                                      nullptr, nullptr, nullptr, nullptr, invn,
                                      rawA, ss0, ss0 + 128, n);

  // layer 1
  k_gemm<<<nblk, 256, 0, stream>>>(nullptr, rawA, wt + (size_t)DIM * 64, dinv,
                                   ss0, ss0 + 128, G[0], Bt[0], invn, xw, n);
  k_agg<<<AGG_GRID, 256, 0, stream>>>(xw, coff, csr_src, dinv, B[1], rawA,
                                      ss0, ss0 + 128, G[0], Bt[0], invn,
                                      rawB, ss1, ss1 + 128, n);

  // layer 2
  k_gemm<<<nblk, 256, 0, stream>>>(nullptr, rawB, wt + (size_t)2 * DIM * 64, dinv,
                                   ss1, ss1 + 128, G[1], Bt[1], invn, xw, n);
  k_agg<<<AGG_GRID, 256, 0, stream>>>(xw, coff, csr_src, dinv, B[2], rawB,
                                      ss1, ss1 + 128, G[1], Bt[1], invn,
                                      rawA, ss2, ss2 + 128, n);

  // final normalize into d_out
  k_norm<<<2048, 256, 0, stream>>>(rawA, out, ss2, ss2 + 128, G[2], Bt[2], invn, n * 32);
}